// Round 1
// baseline (1999.036 us; speedup 1.0000x reference)
//
#include <hip/hip_runtime.h>
#include <math.h>

namespace {

constexpr int Bb = 4;
constexpr int Tt = 2048;
constexpr int Dd = 1024;
constexpr int BT = Bb * Tt;   // 8192

// ---------------------------------------------------------------------------
// Kernel 1: fused QKV projection.  X[BT,D] @ {Wq,Wk,Wv}[D,D] -> QKV[3][BT][D]
// 128x128 tile, BK=8, 256 threads, 8x8 microtile per thread.
// ---------------------------------------------------------------------------
__global__ __launch_bounds__(256) void qkv_gemm_kernel(
    const float* __restrict__ X,
    const float* __restrict__ Wq,
    const float* __restrict__ Wk,
    const float* __restrict__ Wv,
    float* __restrict__ QKV)
{
    __shared__ float As[8][128];
    __shared__ float Bs[8][128];

    const int bx = blockIdx.x;          // 24 n-blocks over 3*D
    const int by = blockIdx.y;          // 64 m-blocks over BT
    const int mat = bx >> 3;            // 0=Q 1=K 2=V
    const int n0 = (bx & 7) * 128;
    const int m0 = by * 128;
    const float* Wm = (mat == 0) ? Wq : (mat == 1) ? Wk : Wv;
    float* Out = QKV + (size_t)mat * BT * Dd;

    const int tid = threadIdx.x;
    const int tx = tid & 15;
    const int ty = tid >> 4;
    const int a_row = tid >> 1;
    const int a_col = (tid & 1) * 4;
    const int b_row = tid >> 5;
    const int b_col = (tid & 31) * 4;

    float acc[8][8];
#pragma unroll
    for (int i = 0; i < 8; ++i)
#pragma unroll
        for (int j = 0; j < 8; ++j) acc[i][j] = 0.f;

    for (int k0 = 0; k0 < Dd; k0 += 8) {
        const float4 av = *(const float4*)(X + (size_t)(m0 + a_row) * Dd + k0 + a_col);
        const float4 bv = *(const float4*)(Wm + (size_t)(k0 + b_row) * Dd + n0 + b_col);
        __syncthreads();
        As[a_col + 0][a_row] = av.x;
        As[a_col + 1][a_row] = av.y;
        As[a_col + 2][a_row] = av.z;
        As[a_col + 3][a_row] = av.w;
        *(float4*)&Bs[b_row][b_col] = bv;
        __syncthreads();
#pragma unroll
        for (int kk = 0; kk < 8; ++kk) {
            const float4 a0 = *(const float4*)&As[kk][ty * 8];
            const float4 a1 = *(const float4*)&As[kk][ty * 8 + 4];
            const float4 b0 = *(const float4*)&Bs[kk][tx * 8];
            const float4 b1 = *(const float4*)&Bs[kk][tx * 8 + 4];
            const float a[8] = {a0.x, a0.y, a0.z, a0.w, a1.x, a1.y, a1.z, a1.w};
            const float b[8] = {b0.x, b0.y, b0.z, b0.w, b1.x, b1.y, b1.z, b1.w};
#pragma unroll
            for (int i = 0; i < 8; ++i)
#pragma unroll
                for (int j = 0; j < 8; ++j)
                    acc[i][j] = fmaf(a[i], b[j], acc[i][j]);
        }
    }
#pragma unroll
    for (int i = 0; i < 8; ++i) {
        float* dst = Out + (size_t)(m0 + ty * 8 + i) * Dd + n0 + tx * 8;
        *(float4*)dst = make_float4(acc[i][0], acc[i][1], acc[i][2], acc[i][3]);
        *(float4*)(dst + 4) = make_float4(acc[i][4], acc[i][5], acc[i][6], acc[i][7]);
    }
}

// ---------------------------------------------------------------------------
// Kernel 2: S[b,q,j] = floor( dot(Q[b,q,:],K[b,j,:]) / 32 )   (j<=q) else -inf
// Fully-masked tiles (bx>by) just store -inf.
// ---------------------------------------------------------------------------
__global__ __launch_bounds__(256) void scores_kernel(
    const float* __restrict__ Q,
    const float* __restrict__ Km,
    float* __restrict__ S)
{
    const int bx = blockIdx.x;          // 16 j-blocks
    const int by = blockIdx.y;          // 16 q-blocks
    const int b  = blockIdx.z;
    const int j0 = bx * 128;
    const int q0 = by * 128;
    float* Sb = S + (size_t)b * Tt * Tt;

    const int tid = threadIdx.x;
    const int tx = tid & 15;
    const int ty = tid >> 4;

    if (bx > by) {  // entirely above the diagonal -> all masked
        const float4 ninf4 = make_float4(-INFINITY, -INFINITY, -INFINITY, -INFINITY);
#pragma unroll
        for (int i = 0; i < 8; ++i) {
            float* dst = Sb + (size_t)(q0 + ty * 8 + i) * Tt + j0 + tx * 8;
            *(float4*)dst = ninf4;
            *(float4*)(dst + 4) = ninf4;
        }
        return;
    }

    __shared__ float As[8][128];
    __shared__ float Bs[8][128];
    const float* Qb = Q + (size_t)b * Tt * Dd;
    const float* Kb = Km + (size_t)b * Tt * Dd;

    const int a_row = tid >> 1;
    const int a_col = (tid & 1) * 4;

    float acc[8][8];
#pragma unroll
    for (int i = 0; i < 8; ++i)
#pragma unroll
        for (int j = 0; j < 8; ++j) acc[i][j] = 0.f;

    for (int k0 = 0; k0 < Dd; k0 += 8) {
        const float4 av = *(const float4*)(Qb + (size_t)(q0 + a_row) * Dd + k0 + a_col);
        const float4 bv = *(const float4*)(Kb + (size_t)(j0 + a_row) * Dd + k0 + a_col);
        __syncthreads();
        As[a_col + 0][a_row] = av.x;
        As[a_col + 1][a_row] = av.y;
        As[a_col + 2][a_row] = av.z;
        As[a_col + 3][a_row] = av.w;
        Bs[a_col + 0][a_row] = bv.x;
        Bs[a_col + 1][a_row] = bv.y;
        Bs[a_col + 2][a_row] = bv.z;
        Bs[a_col + 3][a_row] = bv.w;
        __syncthreads();
#pragma unroll
        for (int kk = 0; kk < 8; ++kk) {
            const float4 a0 = *(const float4*)&As[kk][ty * 8];
            const float4 a1 = *(const float4*)&As[kk][ty * 8 + 4];
            const float4 b0 = *(const float4*)&Bs[kk][tx * 8];
            const float4 b1 = *(const float4*)&Bs[kk][tx * 8 + 4];
            const float a[8] = {a0.x, a0.y, a0.z, a0.w, a1.x, a1.y, a1.z, a1.w};
            const float b[8] = {b0.x, b0.y, b0.z, b0.w, b1.x, b1.y, b1.z, b1.w};
#pragma unroll
            for (int i = 0; i < 8; ++i)
#pragma unroll
                for (int j = 0; j < 8; ++j)
                    acc[i][j] = fmaf(a[i], b[j], acc[i][j]);
        }
    }
#pragma unroll
    for (int i = 0; i < 8; ++i) {
        const int q = q0 + ty * 8 + i;
        float out[8];
#pragma unroll
        for (int j = 0; j < 8; ++j) {
            const int jg = j0 + tx * 8 + j;
            // exact: /32 == *0.03125 (power of two)
            out[j] = (jg <= q) ? floorf(acc[i][j] * 0.03125f) : -INFINITY;
        }
        float* dst = Sb + (size_t)q * Tt + j0 + tx * 8;
        *(float4*)dst = make_float4(out[0], out[1], out[2], out[3]);
        *(float4*)(dst + 4) = make_float4(out[4], out[5], out[6], out[7]);
    }
}

// ---------------------------------------------------------------------------
// Kernel 2b: per-(b,j) softmax stats over q (axis=1 softmax!).
// One thread per column j; coalesced row sweep starting at block diagonal.
// ---------------------------------------------------------------------------
__global__ __launch_bounds__(256) void colstats_kernel(
    const float* __restrict__ S,
    float* __restrict__ Mb,
    float* __restrict__ Lb)
{
    const int j = blockIdx.x * 256 + threadIdx.x;
    const int b = blockIdx.y;
    const float* Sb = S + (size_t)b * Tt * Tt;
    const int qstart = blockIdx.x * 256;   // rows q < j are all -inf; uniform start
    float m = -INFINITY;
    float l = 0.f;
    for (int q = qstart; q < Tt; ++q) {
        const float s = Sb[(size_t)q * Tt + j];
        if (s != -INFINITY) {
            if (s > m) { l *= __expf(m - s); m = s; }
            l += __expf(s - m);
        }
    }
    Mb[(size_t)b * Tt + j] = m;
    Lb[(size_t)b * Tt + j] = 1.f / l;
}

// ---------------------------------------------------------------------------
// Kernel 3: context[b,q,d] = sum_j exp(S[q,j]-m[j])*invl[j] * V[j,d]
// Same tiled GEMM; exp/normalize fused into A-tile load; K-loop stops at the
// causal boundary (w==0 for j>q).  Heavy q-blocks dispatched first.
// ---------------------------------------------------------------------------
__global__ __launch_bounds__(256) void context_kernel(
    const float* __restrict__ S,
    const float* __restrict__ V,
    const float* __restrict__ Mb,
    const float* __restrict__ Lb,
    float* __restrict__ Out)
{
    __shared__ float As[8][128];
    __shared__ float Bs[8][128];

    const int bx = blockIdx.x;                       // 8 d-blocks
    const int by = (int)gridDim.y - 1 - blockIdx.y;  // 16 q-blocks, heavy first
    const int b  = blockIdx.z;
    const int d0 = bx * 128;
    const int q0 = by * 128;
    const float* Sb = S + (size_t)b * Tt * Tt;
    const float* Vb = V + (size_t)b * Tt * Dd;
    const float* mb = Mb + (size_t)b * Tt;
    const float* lb = Lb + (size_t)b * Tt;
    float* Ob = Out + (size_t)b * Tt * Dd;

    const int tid = threadIdx.x;
    const int tx = tid & 15;
    const int ty = tid >> 4;
    const int a_row = tid >> 1;
    const int a_col = (tid & 1) * 4;
    const int b_row = tid >> 5;
    const int b_col = (tid & 31) * 4;

    float acc[8][8];
#pragma unroll
    for (int i = 0; i < 8; ++i)
#pragma unroll
        for (int j = 0; j < 8; ++j) acc[i][j] = 0.f;

    const int kmax = q0 + 128;   // for j >= q0+128 all weights in this q-tile are 0
    for (int k0 = 0; k0 < kmax; k0 += 8) {
        const float4 sv = *(const float4*)(Sb + (size_t)(q0 + a_row) * Tt + k0 + a_col);
        const float4 vv = *(const float4*)(Vb + (size_t)(k0 + b_row) * Dd + d0 + b_col);
        float w[4];
        {
            const float sarr[4] = {sv.x, sv.y, sv.z, sv.w};
#pragma unroll
            for (int i = 0; i < 4; ++i) {
                const int jg = k0 + a_col + i;
                // s==-inf -> exp(-inf)=0 -> masked entries contribute nothing
                w[i] = __expf(sarr[i] - mb[jg]) * lb[jg];
            }
        }
        __syncthreads();
        As[a_col + 0][a_row] = w[0];
        As[a_col + 1][a_row] = w[1];
        As[a_col + 2][a_row] = w[2];
        As[a_col + 3][a_row] = w[3];
        *(float4*)&Bs[b_row][b_col] = vv;
        __syncthreads();
#pragma unroll
        for (int kk = 0; kk < 8; ++kk) {
            const float4 a0 = *(const float4*)&As[kk][ty * 8];
            const float4 a1 = *(const float4*)&As[kk][ty * 8 + 4];
            const float4 b0 = *(const float4*)&Bs[kk][tx * 8];
            const float4 b1 = *(const float4*)&Bs[kk][tx * 8 + 4];
            const float a[8] = {a0.x, a0.y, a0.z, a0.w, a1.x, a1.y, a1.z, a1.w};
            const float b[8] = {b0.x, b0.y, b0.z, b0.w, b1.x, b1.y, b1.z, b1.w};
#pragma unroll
            for (int i = 0; i < 8; ++i)
#pragma unroll
                for (int j = 0; j < 8; ++j)
                    acc[i][j] = fmaf(a[i], b[j], acc[i][j]);
        }
    }
#pragma unroll
    for (int i = 0; i < 8; ++i) {
        float* dst = Ob + (size_t)(q0 + ty * 8 + i) * Dd + d0 + tx * 8;
        *(float4*)dst = make_float4(acc[i][0], acc[i][1], acc[i][2], acc[i][3]);
        *(float4*)(dst + 4) = make_float4(acc[i][4], acc[i][5], acc[i][6], acc[i][7]);
    }
}

}  // namespace

extern "C" void kernel_launch(void* const* d_in, const int* in_sizes, int n_in,
                              void* d_out, int out_size, void* d_ws, size_t ws_size,
                              hipStream_t stream)
{
    const float* X  = (const float*)d_in[0];
    const float* Wq = (const float*)d_in[1];
    const float* Wk = (const float*)d_in[2];
    const float* Wv = (const float*)d_in[3];

    // workspace layout (floats): Q | K | V | S | m | invl  = ~168 MB
    float* ws = (float*)d_ws;
    float* Q  = ws;
    float* Km = Q  + (size_t)BT * Dd;
    float* V  = Km + (size_t)BT * Dd;
    float* S  = V  + (size_t)BT * Dd;
    float* Mb = S  + (size_t)Bb * Tt * Tt;
    float* Lb = Mb + (size_t)Bb * Tt;
    float* Out = (float*)d_out;

    qkv_gemm_kernel<<<dim3(24, 64), 256, 0, stream>>>(X, Wq, Wk, Wv, Q);
    scores_kernel<<<dim3(16, 16, Bb), 256, 0, stream>>>(Q, Km, S);
    colstats_kernel<<<dim3(Tt / 256, Bb), 256, 0, stream>>>(S, Mb, Lb);
    context_kernel<<<dim3(Dd / 128, Tt / 128, Bb), 256, 0, stream>>>(S, V, Mb, Lb, Out);
}

// Round 2
// 1410.677 us; speedup vs baseline: 1.4171x; 1.4171x over previous
//
#include <hip/hip_runtime.h>
#include <math.h>

namespace {

constexpr int Bb = 4;
constexpr int Tt = 2048;
constexpr int Dd = 1024;
constexpr int BT = Bb * Tt;   // 8192

// Column-split mapping: each thread's 8 output columns are n0+tx*4..+3 and
// n0+64+tx*4..+3.  LDS B-reads at tx*4 stride -> 2-way bank aliasing (free)
// instead of the 4-way conflict of the tx*8 mapping.

// ---------------------------------------------------------------------------
// Kernel 1: fused QKV projection.  X[BT,D] @ {Wq,Wk,Wv}[D,D] -> QKV[3][BT][D]
// ---------------------------------------------------------------------------
__global__ __launch_bounds__(256) void qkv_gemm_kernel(
    const float* __restrict__ X,
    const float* __restrict__ Wq,
    const float* __restrict__ Wk,
    const float* __restrict__ Wv,
    float* __restrict__ QKV)
{
    __shared__ float As[8][128];
    __shared__ float Bs[8][128];

    const int bx = blockIdx.x;          // 24 n-blocks over 3*D
    const int by = blockIdx.y;          // 64 m-blocks over BT
    const int mat = bx >> 3;            // 0=Q 1=K 2=V
    const int n0 = (bx & 7) * 128;
    const int m0 = by * 128;
    const float* Wm = (mat == 0) ? Wq : (mat == 1) ? Wk : Wv;
    float* Out = QKV + (size_t)mat * BT * Dd;

    const int tid = threadIdx.x;
    const int tx = tid & 15;
    const int ty = tid >> 4;
    const int a_row = tid >> 1;
    const int a_col = (tid & 1) * 4;
    const int b_row = tid >> 5;
    const int b_col = (tid & 31) * 4;

    float acc[8][8];
#pragma unroll
    for (int i = 0; i < 8; ++i)
#pragma unroll
        for (int j = 0; j < 8; ++j) acc[i][j] = 0.f;

    for (int k0 = 0; k0 < Dd; k0 += 8) {
        const float4 av = *(const float4*)(X + (size_t)(m0 + a_row) * Dd + k0 + a_col);
        const float4 bv = *(const float4*)(Wm + (size_t)(k0 + b_row) * Dd + n0 + b_col);
        __syncthreads();
        As[a_col + 0][a_row] = av.x;
        As[a_col + 1][a_row] = av.y;
        As[a_col + 2][a_row] = av.z;
        As[a_col + 3][a_row] = av.w;
        *(float4*)&Bs[b_row][b_col] = bv;
        __syncthreads();
#pragma unroll
        for (int kk = 0; kk < 8; ++kk) {
            const float4 a0 = *(const float4*)&As[kk][ty * 8];
            const float4 a1 = *(const float4*)&As[kk][ty * 8 + 4];
            const float4 b0 = *(const float4*)&Bs[kk][tx * 4];
            const float4 b1 = *(const float4*)&Bs[kk][64 + tx * 4];
            const float a[8] = {a0.x, a0.y, a0.z, a0.w, a1.x, a1.y, a1.z, a1.w};
            const float b[8] = {b0.x, b0.y, b0.z, b0.w, b1.x, b1.y, b1.z, b1.w};
#pragma unroll
            for (int i = 0; i < 8; ++i)
#pragma unroll
                for (int j = 0; j < 8; ++j)
                    acc[i][j] = fmaf(a[i], b[j], acc[i][j]);
        }
    }
#pragma unroll
    for (int i = 0; i < 8; ++i) {
        float* dst = Out + (size_t)(m0 + ty * 8 + i) * Dd + n0;
        *(float4*)(dst + tx * 4) = make_float4(acc[i][0], acc[i][1], acc[i][2], acc[i][3]);
        *(float4*)(dst + 64 + tx * 4) = make_float4(acc[i][4], acc[i][5], acc[i][6], acc[i][7]);
    }
}

// ---------------------------------------------------------------------------
// Kernel 2: S[b,q,j] = floor( dot(Q[b,q,:],K[b,j,:]) / 32 )   (j<=q) else -inf
// ---------------------------------------------------------------------------
__global__ __launch_bounds__(256) void scores_kernel(
    const float* __restrict__ Q,
    const float* __restrict__ Km,
    float* __restrict__ S)
{
    const int bx = blockIdx.x;          // 16 j-blocks
    const int by = blockIdx.y;          // 16 q-blocks
    const int b  = blockIdx.z;
    const int j0 = bx * 128;
    const int q0 = by * 128;
    float* Sb = S + (size_t)b * Tt * Tt;

    const int tid = threadIdx.x;
    const int tx = tid & 15;
    const int ty = tid >> 4;

    if (bx > by) {  // entirely above the diagonal -> all masked
        const float4 ninf4 = make_float4(-INFINITY, -INFINITY, -INFINITY, -INFINITY);
#pragma unroll
        for (int i = 0; i < 8; ++i) {
            float* dst = Sb + (size_t)(q0 + ty * 8 + i) * Tt + j0 + tx * 8;
            *(float4*)dst = ninf4;
            *(float4*)(dst + 4) = ninf4;
        }
        return;
    }

    __shared__ float As[8][128];
    __shared__ float Bs[8][128];
    const float* Qb = Q + (size_t)b * Tt * Dd;
    const float* Kb = Km + (size_t)b * Tt * Dd;

    const int a_row = tid >> 1;
    const int a_col = (tid & 1) * 4;

    float acc[8][8];
#pragma unroll
    for (int i = 0; i < 8; ++i)
#pragma unroll
        for (int j = 0; j < 8; ++j) acc[i][j] = 0.f;

    for (int k0 = 0; k0 < Dd; k0 += 8) {
        const float4 av = *(const float4*)(Qb + (size_t)(q0 + a_row) * Dd + k0 + a_col);
        const float4 bv = *(const float4*)(Kb + (size_t)(j0 + a_row) * Dd + k0 + a_col);
        __syncthreads();
        As[a_col + 0][a_row] = av.x;
        As[a_col + 1][a_row] = av.y;
        As[a_col + 2][a_row] = av.z;
        As[a_col + 3][a_row] = av.w;
        Bs[a_col + 0][a_row] = bv.x;
        Bs[a_col + 1][a_row] = bv.y;
        Bs[a_col + 2][a_row] = bv.z;
        Bs[a_col + 3][a_row] = bv.w;
        __syncthreads();
#pragma unroll
        for (int kk = 0; kk < 8; ++kk) {
            const float4 a0 = *(const float4*)&As[kk][ty * 8];
            const float4 a1 = *(const float4*)&As[kk][ty * 8 + 4];
            const float4 b0 = *(const float4*)&Bs[kk][tx * 4];
            const float4 b1 = *(const float4*)&Bs[kk][64 + tx * 4];
            const float a[8] = {a0.x, a0.y, a0.z, a0.w, a1.x, a1.y, a1.z, a1.w};
            const float b[8] = {b0.x, b0.y, b0.z, b0.w, b1.x, b1.y, b1.z, b1.w};
#pragma unroll
            for (int i = 0; i < 8; ++i)
#pragma unroll
                for (int j = 0; j < 8; ++j)
                    acc[i][j] = fmaf(a[i], b[j], acc[i][j]);
        }
    }
#pragma unroll
    for (int i = 0; i < 8; ++i) {
        const int q = q0 + ty * 8 + i;
        float out0[4], out1[4];
#pragma unroll
        for (int j = 0; j < 4; ++j) {
            const int jg = j0 + tx * 4 + j;
            out0[j] = (jg <= q) ? floorf(acc[i][j] * 0.03125f) : -INFINITY;
        }
#pragma unroll
        for (int j = 0; j < 4; ++j) {
            const int jg = j0 + 64 + tx * 4 + j;
            out1[j] = (jg <= q) ? floorf(acc[i][j + 4] * 0.03125f) : -INFINITY;
        }
        float* dst = Sb + (size_t)q * Tt + j0;
        *(float4*)(dst + tx * 4) = make_float4(out0[0], out0[1], out0[2], out0[3]);
        *(float4*)(dst + 64 + tx * 4) = make_float4(out1[0], out1[1], out1[2], out1[3]);
    }
}

// ---------------------------------------------------------------------------
// Kernel 2b phase 1: partial softmax stats over 64-row q-chunks.
// grid (Tt/256 j-blocks, Tt/64 q-chunks, Bb). 256 threads, 1 col/thread.
// ---------------------------------------------------------------------------
constexpr int QCH = 64;                       // rows per chunk
constexpr int NCH = Tt / QCH;                 // 32 chunks

__global__ __launch_bounds__(256) void colstats_part_kernel(
    const float* __restrict__ S,
    float* __restrict__ Pm,
    float* __restrict__ Pl)
{
    const int jb = blockIdx.x;
    const int qc = blockIdx.y;
    const int b  = blockIdx.z;
    const int j  = jb * 256 + threadIdx.x;
    const int r0 = qc * QCH;
    const size_t pidx = ((size_t)b * NCH + qc) * Tt + j;

    // entirely above the diagonal: rows r0..r0+63 all < smallest j in block
    if (r0 + QCH <= jb * 256) {
        Pm[pidx] = -INFINITY;
        Pl[pidx] = 0.f;
        return;
    }
    const float* Sb = S + (size_t)b * Tt * Tt;
    float m = -INFINITY;
    float l = 0.f;
    for (int q = r0; q < r0 + QCH; ++q) {
        const float s = Sb[(size_t)q * Tt + j];
        if (s != -INFINITY) {
            if (s > m) { l *= __expf(m - s); m = s; }
            l += __expf(s - m);
        }
    }
    Pm[pidx] = m;
    Pl[pidx] = l;
}

// phase 2: merge NCH partials per column -> m, 1/l
__global__ __launch_bounds__(256) void colstats_merge_kernel(
    const float* __restrict__ Pm,
    const float* __restrict__ Pl,
    float* __restrict__ Mb,
    float* __restrict__ Lb)
{
    const int j = blockIdx.x * 256 + threadIdx.x;
    const int b = blockIdx.y;
    float m = -INFINITY;
    float l = 0.f;
#pragma unroll 4
    for (int c = 0; c < NCH; ++c) {
        const size_t pidx = ((size_t)b * NCH + c) * Tt + j;
        const float mi = Pm[pidx];
        if (mi == -INFINITY) continue;
        const float li = Pl[pidx];
        if (mi > m) { l = l * __expf(m - mi) + li; m = mi; }
        else        { l += li * __expf(mi - m); }
    }
    Mb[(size_t)b * Tt + j] = m;
    Lb[(size_t)b * Tt + j] = (l > 0.f) ? 1.f / l : 0.f;
}

// ---------------------------------------------------------------------------
// Kernel 3: context[b,q,d] = sum_j exp(S[q,j]-m[j])*invl[j] * V[j,d]
// ---------------------------------------------------------------------------
__global__ __launch_bounds__(256) void context_kernel(
    const float* __restrict__ S,
    const float* __restrict__ V,
    const float* __restrict__ Mb,
    const float* __restrict__ Lb,
    float* __restrict__ Out)
{
    __shared__ float As[8][128];
    __shared__ float Bs[8][128];

    const int bx = blockIdx.x;                       // 8 d-blocks
    const int by = (int)gridDim.y - 1 - blockIdx.y;  // 16 q-blocks, heavy first
    const int b  = blockIdx.z;
    const int d0 = bx * 128;
    const int q0 = by * 128;
    const float* Sb = S + (size_t)b * Tt * Tt;
    const float* Vb = V + (size_t)b * Tt * Dd;
    const float* mb = Mb + (size_t)b * Tt;
    const float* lb = Lb + (size_t)b * Tt;
    float* Ob = Out + (size_t)b * Tt * Dd;

    const int tid = threadIdx.x;
    const int tx = tid & 15;
    const int ty = tid >> 4;
    const int a_row = tid >> 1;
    const int a_col = (tid & 1) * 4;
    const int b_row = tid >> 5;
    const int b_col = (tid & 31) * 4;

    float acc[8][8];
#pragma unroll
    for (int i = 0; i < 8; ++i)
#pragma unroll
        for (int j = 0; j < 8; ++j) acc[i][j] = 0.f;

    const int kmax = q0 + 128;   // for j >= q0+128 all weights in this q-tile are 0
    for (int k0 = 0; k0 < kmax; k0 += 8) {
        const float4 sv = *(const float4*)(Sb + (size_t)(q0 + a_row) * Tt + k0 + a_col);
        const float4 vv = *(const float4*)(Vb + (size_t)(k0 + b_row) * Dd + d0 + b_col);
        float w[4];
        {
            const float sarr[4] = {sv.x, sv.y, sv.z, sv.w};
#pragma unroll
            for (int i = 0; i < 4; ++i) {
                const int jg = k0 + a_col + i;
                w[i] = __expf(sarr[i] - mb[jg]) * lb[jg];
            }
        }
        __syncthreads();
        As[a_col + 0][a_row] = w[0];
        As[a_col + 1][a_row] = w[1];
        As[a_col + 2][a_row] = w[2];
        As[a_col + 3][a_row] = w[3];
        *(float4*)&Bs[b_row][b_col] = vv;
        __syncthreads();
#pragma unroll
        for (int kk = 0; kk < 8; ++kk) {
            const float4 a0 = *(const float4*)&As[kk][ty * 8];
            const float4 a1 = *(const float4*)&As[kk][ty * 8 + 4];
            const float4 b0 = *(const float4*)&Bs[kk][tx * 4];
            const float4 b1 = *(const float4*)&Bs[kk][64 + tx * 4];
            const float a[8] = {a0.x, a0.y, a0.z, a0.w, a1.x, a1.y, a1.z, a1.w};
            const float b[8] = {b0.x, b0.y, b0.z, b0.w, b1.x, b1.y, b1.z, b1.w};
#pragma unroll
            for (int i = 0; i < 8; ++i)
#pragma unroll
                for (int j = 0; j < 8; ++j)
                    acc[i][j] = fmaf(a[i], b[j], acc[i][j]);
        }
    }
#pragma unroll
    for (int i = 0; i < 8; ++i) {
        float* dst = Ob + (size_t)(q0 + ty * 8 + i) * Dd + d0;
        *(float4*)(dst + tx * 4) = make_float4(acc[i][0], acc[i][1], acc[i][2], acc[i][3]);
        *(float4*)(dst + 64 + tx * 4) = make_float4(acc[i][4], acc[i][5], acc[i][6], acc[i][7]);
    }
}

}  // namespace

extern "C" void kernel_launch(void* const* d_in, const int* in_sizes, int n_in,
                              void* d_out, int out_size, void* d_ws, size_t ws_size,
                              hipStream_t stream)
{
    const float* X  = (const float*)d_in[0];
    const float* Wq = (const float*)d_in[1];
    const float* Wk = (const float*)d_in[2];
    const float* Wv = (const float*)d_in[3];

    // workspace layout (floats): Q | K | V | S | m | invl | Pm | Pl  (~161 MB)
    float* ws = (float*)d_ws;
    float* Q  = ws;
    float* Km = Q  + (size_t)BT * Dd;
    float* V  = Km + (size_t)BT * Dd;
    float* S  = V  + (size_t)BT * Dd;
    float* Mb = S  + (size_t)Bb * Tt * Tt;
    float* Lb = Mb + (size_t)Bb * Tt;
    float* Pm = Lb + (size_t)Bb * Tt;
    float* Pl = Pm + (size_t)Bb * NCH * Tt;
    float* Out = (float*)d_out;

    qkv_gemm_kernel<<<dim3(24, 64), 256, 0, stream>>>(X, Wq, Wk, Wv, Q);
    scores_kernel<<<dim3(16, 16, Bb), 256, 0, stream>>>(Q, Km, S);
    colstats_part_kernel<<<dim3(Tt / 256, NCH, Bb), 256, 0, stream>>>(S, Pm, Pl);
    colstats_merge_kernel<<<dim3(Tt / 256, Bb), 256, 0, stream>>>(Pm, Pl, Mb, Lb);
    context_kernel<<<dim3(Dd / 128, Tt / 128, Bb), 256, 0, stream>>>(S, V, Mb, Lb, Out);
}

// Round 3
// 1243.359 us; speedup vs baseline: 1.6078x; 1.1346x over previous
//
#include <hip/hip_runtime.h>
#include <math.h>

typedef short short8 __attribute__((ext_vector_type(8)));
typedef float f32x4 __attribute__((ext_vector_type(4)));

namespace {

constexpr int Bb = 4;
constexpr int Tt = 2048;
constexpr int Dd = 1024;
constexpr int BT = Bb * Tt;   // 8192

// ---- fp32 -> 2x bf16 split helpers (RNE) ----
__device__ inline unsigned short f2bf(float f) {
    unsigned int x = __float_as_uint(f);
    unsigned int r = (x + 0x7fffu + ((x >> 16) & 1u)) >> 16;
    return (unsigned short)r;
}
__device__ inline float bf2f(unsigned short h) {
    return __uint_as_float(((unsigned int)h) << 16);
}

// ---------------------------------------------------------------------------
// convert X: fp32 [BT][D] -> Xhi, Xlo bf16
// ---------------------------------------------------------------------------
__global__ __launch_bounds__(256) void convert_x_kernel(
    const float* __restrict__ X, ushort* __restrict__ Xhi, ushort* __restrict__ Xlo)
{
    const int idx = (blockIdx.x * 256 + threadIdx.x) * 4;
    const float4 v = *(const float4*)(X + idx);
    const float a[4] = {v.x, v.y, v.z, v.w};
    ushort h[4], l[4];
#pragma unroll
    for (int i = 0; i < 4; ++i) {
        h[i] = f2bf(a[i]);
        l[i] = f2bf(a[i] - bf2f(h[i]));
    }
    *(ushort4*)(Xhi + idx) = make_ushort4(h[0], h[1], h[2], h[3]);
    *(ushort4*)(Xlo + idx) = make_ushort4(l[0], l[1], l[2], l[3]);
}

// ---------------------------------------------------------------------------
// convert+transpose W: fp32 W[k][n] -> Whit[n][k], Wlot[n][k] bf16 (3 mats)
// ---------------------------------------------------------------------------
__global__ __launch_bounds__(256) void convert_w_kernel(
    const float* __restrict__ W0, const float* __restrict__ W1,
    const float* __restrict__ W2,
    ushort* __restrict__ Whit, ushort* __restrict__ Wlot)
{
    const int mat = blockIdx.z;
    const float* W = (mat == 0) ? W0 : (mat == 1) ? W1 : W2;
    ushort* Ht = Whit + (size_t)mat * Dd * Dd;
    ushort* Lt = Wlot + (size_t)mat * Dd * Dd;
    __shared__ float tile[64][65];
    const int n0 = blockIdx.x * 64, k0 = blockIdx.y * 64;
    const int tx = threadIdx.x & 63, ty = threadIdx.x >> 6;
#pragma unroll
    for (int i = 0; i < 16; ++i)
        tile[ty + i * 4][tx] = W[(size_t)(k0 + ty + i * 4) * Dd + n0 + tx];
    __syncthreads();
#pragma unroll
    for (int i = 0; i < 16; ++i) {
        const float v = tile[tx][ty + i * 4];           // = W[k0+tx][n0+ty+i*4]
        const size_t o = (size_t)(n0 + ty + i * 4) * Dd + k0 + tx;
        const ushort h = f2bf(v);
        Ht[o] = h;
        Lt[o] = f2bf(v - bf2f(h));
    }
}

// ---------------------------------------------------------------------------
// Split-bf16 MFMA GEMM core pattern:
//   128x128 tile, 4 waves, each wave 4x4 tiles of 16x16x32 MFMA.
//   LDS fragment-blocked: sub-tile s (16 rows x 32 k) = 64 lanes x 16B at
//   Al[s][lane*8]; staged by global_load_lds width=16 (dest = base+lane*16).
//   K' = 4096: pass = k0>>10 selects (hi,hi),(hi,lo),(lo,hi),(lo,lo).
// ---------------------------------------------------------------------------

// Kernel 1: QKV.  A = X splits [BT][1024], B = W^T splits [n][k].
// mats 0,1 -> write Q/K as hi/lo bf16; mat 2 -> write V fp32.
__global__ __launch_bounds__(256) void qkv_mfma_kernel(
    const ushort* __restrict__ Xhi, const ushort* __restrict__ Xlo,
    const ushort* __restrict__ Whit, const ushort* __restrict__ Wlot,
    ushort* __restrict__ Qhi, ushort* __restrict__ Qlo,
    ushort* __restrict__ Khi, ushort* __restrict__ Klo,
    float* __restrict__ Vf)
{
    __shared__ ushort Al[8][512];
    __shared__ ushort Bl[8][512];

    const int mat = blockIdx.x >> 3;
    const int n0 = (blockIdx.x & 7) * 128;
    const int m0 = blockIdx.y * 128;
    const ushort* WhT = Whit + (size_t)mat * Dd * Dd;
    const ushort* WlT = Wlot + (size_t)mat * Dd * Dd;

    const int tid = threadIdx.x;
    const int w = tid >> 6, lane = tid & 63;
    const int lr = lane & 15, lq = lane >> 4;
    const int wr = (w >> 1) * 4, wc = (w & 1) * 4;

    f32x4 acc[4][4];
#pragma unroll
    for (int i = 0; i < 4; ++i)
#pragma unroll
        for (int j = 0; j < 4; ++j)
#pragma unroll
            for (int c = 0; c < 4; ++c) acc[i][j][c] = 0.f;

    for (int k0 = 0; k0 < 4096; k0 += 32) {
        const int pass = k0 >> 10;
        const int kk = k0 & 1023;
        const ushort* Ap = (pass < 2) ? Xhi : Xlo;
        const ushort* Bp = (pass & 1) ? WlT : WhT;
        __syncthreads();
#pragma unroll
        for (int s2 = 0; s2 < 2; ++s2) {
            const int s = w * 2 + s2;
            const ushort* ga = Ap + (size_t)(m0 + s * 16 + lr) * Dd + kk + lq * 8;
            const ushort* gb = Bp + (size_t)(n0 + s * 16 + lr) * Dd + kk + lq * 8;
            __builtin_amdgcn_global_load_lds(
                (const __attribute__((address_space(1))) unsigned int*)ga,
                (__attribute__((address_space(3))) unsigned int*)&Al[s][0], 16, 0, 0);
            __builtin_amdgcn_global_load_lds(
                (const __attribute__((address_space(1))) unsigned int*)gb,
                (__attribute__((address_space(3))) unsigned int*)&Bl[s][0], 16, 0, 0);
        }
        __syncthreads();
        short8 a[4], b[4];
#pragma unroll
        for (int i = 0; i < 4; ++i) a[i] = *(const short8*)&Al[wr + i][lane * 8];
#pragma unroll
        for (int j = 0; j < 4; ++j) b[j] = *(const short8*)&Bl[wc + j][lane * 8];
#pragma unroll
        for (int i = 0; i < 4; ++i)
#pragma unroll
            for (int j = 0; j < 4; ++j)
                acc[i][j] = __builtin_amdgcn_mfma_f32_16x16x32_bf16(a[i], b[j], acc[i][j], 0, 0, 0);
    }

    // epilogue: C[row = m0+(wr+i)*16+lq*4+r][col = n0+(wc+j)*16+lr]
    if (mat < 2) {
        ushort* Hh = mat ? Khi : Qhi;
        ushort* Ll = mat ? Klo : Qlo;
#pragma unroll
        for (int i = 0; i < 4; ++i)
#pragma unroll
            for (int r = 0; r < 4; ++r) {
                const int row = m0 + (wr + i) * 16 + lq * 4 + r;
#pragma unroll
                for (int j = 0; j < 4; ++j) {
                    const int col = n0 + (wc + j) * 16 + lr;
                    const float v = acc[i][j][r];
                    const ushort h = f2bf(v);
                    Hh[(size_t)row * Dd + col] = h;
                    Ll[(size_t)row * Dd + col] = f2bf(v - bf2f(h));
                }
            }
    } else {
#pragma unroll
        for (int i = 0; i < 4; ++i)
#pragma unroll
            for (int r = 0; r < 4; ++r) {
                const int row = m0 + (wr + i) * 16 + lq * 4 + r;
#pragma unroll
                for (int j = 0; j < 4; ++j) {
                    const int col = n0 + (wc + j) * 16 + lr;
                    Vf[(size_t)row * Dd + col] = acc[i][j][r];
                }
            }
    }
}

// Kernel 2: scores.  A = Q splits, B = K splits (row-major [t][d] both sides,
// since S = Q.K^T).  Epilogue: floor(s/32) + causal mask -> S fp32.
__global__ __launch_bounds__(256) void scores_mfma_kernel(
    const ushort* __restrict__ Qhi, const ushort* __restrict__ Qlo,
    const ushort* __restrict__ Khi, const ushort* __restrict__ Klo,
    float* __restrict__ S)
{
    const int bxi = blockIdx.x, byi = blockIdx.y, b = blockIdx.z;
    const int j0 = bxi * 128, q0 = byi * 128;
    float* Sb = S + (size_t)b * Tt * Tt;
    const int tid = threadIdx.x;

    if (bxi > byi) {  // fully masked tile
        const int tx = tid & 31, ty = tid >> 5;
        const float4 ninf4 = make_float4(-INFINITY, -INFINITY, -INFINITY, -INFINITY);
#pragma unroll
        for (int i = 0; i < 16; ++i)
            *(float4*)(Sb + (size_t)(q0 + ty * 16 + i) * Tt + j0 + tx * 4) = ninf4;
        return;
    }

    __shared__ ushort Al[8][512];
    __shared__ ushort Bl[8][512];
    const ushort* Qh = Qhi + (size_t)b * Tt * Dd;
    const ushort* Ql = Qlo + (size_t)b * Tt * Dd;
    const ushort* Kh = Khi + (size_t)b * Tt * Dd;
    const ushort* Kl = Klo + (size_t)b * Tt * Dd;

    const int w = tid >> 6, lane = tid & 63;
    const int lr = lane & 15, lq = lane >> 4;
    const int wr = (w >> 1) * 4, wc = (w & 1) * 4;

    f32x4 acc[4][4];
#pragma unroll
    for (int i = 0; i < 4; ++i)
#pragma unroll
        for (int j = 0; j < 4; ++j)
#pragma unroll
            for (int c = 0; c < 4; ++c) acc[i][j][c] = 0.f;

    for (int k0 = 0; k0 < 4096; k0 += 32) {
        const int pass = k0 >> 10;
        const int kk = k0 & 1023;
        const ushort* Ap = (pass < 2) ? Qh : Ql;
        const ushort* Bp = (pass & 1) ? Kl : Kh;
        __syncthreads();
#pragma unroll
        for (int s2 = 0; s2 < 2; ++s2) {
            const int s = w * 2 + s2;
            const ushort* ga = Ap + (size_t)(q0 + s * 16 + lr) * Dd + kk + lq * 8;
            const ushort* gb = Bp + (size_t)(j0 + s * 16 + lr) * Dd + kk + lq * 8;
            __builtin_amdgcn_global_load_lds(
                (const __attribute__((address_space(1))) unsigned int*)ga,
                (__attribute__((address_space(3))) unsigned int*)&Al[s][0], 16, 0, 0);
            __builtin_amdgcn_global_load_lds(
                (const __attribute__((address_space(1))) unsigned int*)gb,
                (__attribute__((address_space(3))) unsigned int*)&Bl[s][0], 16, 0, 0);
        }
        __syncthreads();
        short8 a[4], b2[4];
#pragma unroll
        for (int i = 0; i < 4; ++i) a[i] = *(const short8*)&Al[wr + i][lane * 8];
#pragma unroll
        for (int j = 0; j < 4; ++j) b2[j] = *(const short8*)&Bl[wc + j][lane * 8];
#pragma unroll
        for (int i = 0; i < 4; ++i)
#pragma unroll
            for (int j = 0; j < 4; ++j)
                acc[i][j] = __builtin_amdgcn_mfma_f32_16x16x32_bf16(a[i], b2[j], acc[i][j], 0, 0, 0);
    }

#pragma unroll
    for (int i = 0; i < 4; ++i)
#pragma unroll
        for (int r = 0; r < 4; ++r) {
            const int q = q0 + (wr + i) * 16 + lq * 4 + r;
#pragma unroll
            for (int j = 0; j < 4; ++j) {
                const int jg = j0 + (wc + j) * 16 + lr;
                Sb[(size_t)q * Tt + jg] =
                    (jg <= q) ? floorf(acc[i][j][r] * 0.03125f) : -INFINITY;
            }
        }
}

// ---------------------------------------------------------------------------
// colstats (softmax over the QUERY axis): two-phase segmented reduction
// ---------------------------------------------------------------------------
constexpr int QCH = 64;
constexpr int NCH = Tt / QCH;   // 32

__global__ __launch_bounds__(256) void colstats_part_kernel(
    const float* __restrict__ S, float* __restrict__ Pm, float* __restrict__ Pl)
{
    const int jb = blockIdx.x, qc = blockIdx.y, b = blockIdx.z;
    const int j = jb * 256 + threadIdx.x;
    const int r0 = qc * QCH;
    const size_t pidx = ((size_t)b * NCH + qc) * Tt + j;
    if (r0 + QCH <= jb * 256) { Pm[pidx] = -INFINITY; Pl[pidx] = 0.f; return; }
    const float* Sb = S + (size_t)b * Tt * Tt;
    float m = -INFINITY, l = 0.f;
    for (int q = r0; q < r0 + QCH; ++q) {
        const float s = Sb[(size_t)q * Tt + j];
        if (s != -INFINITY) {
            if (s > m) { l *= __expf(m - s); m = s; }
            l += __expf(s - m);
        }
    }
    Pm[pidx] = m;
    Pl[pidx] = l;
}

__global__ __launch_bounds__(256) void colstats_merge_kernel(
    const float* __restrict__ Pm, const float* __restrict__ Pl,
    float* __restrict__ Mb, float* __restrict__ Lb)
{
    const int j = blockIdx.x * 256 + threadIdx.x;
    const int b = blockIdx.y;
    float m = -INFINITY, l = 0.f;
#pragma unroll 4
    for (int c = 0; c < NCH; ++c) {
        const size_t pidx = ((size_t)b * NCH + c) * Tt + j;
        const float mi = Pm[pidx];
        if (mi == -INFINITY) continue;
        const float li = Pl[pidx];
        if (mi > m) { l = l * __expf(m - mi) + li; m = mi; }
        else        { l += li * __expf(mi - m); }
    }
    Mb[(size_t)b * Tt + j] = m;
    Lb[(size_t)b * Tt + j] = (l > 0.f) ? 1.f / l : 0.f;
}

// ---------------------------------------------------------------------------
// context (fp32 vector GEMM, unchanged from round 1)
// ---------------------------------------------------------------------------
__global__ __launch_bounds__(256) void context_kernel(
    const float* __restrict__ S, const float* __restrict__ V,
    const float* __restrict__ Mb, const float* __restrict__ Lb,
    float* __restrict__ Out)
{
    __shared__ float As[8][128];
    __shared__ float Bs[8][128];

    const int bx = blockIdx.x;
    const int by = (int)gridDim.y - 1 - blockIdx.y;
    const int b  = blockIdx.z;
    const int d0 = bx * 128;
    const int q0 = by * 128;
    const float* Sb = S + (size_t)b * Tt * Tt;
    const float* Vb = V + (size_t)b * Tt * Dd;
    const float* mb = Mb + (size_t)b * Tt;
    const float* lb = Lb + (size_t)b * Tt;
    float* Ob = Out + (size_t)b * Tt * Dd;

    const int tid = threadIdx.x;
    const int tx = tid & 15;
    const int ty = tid >> 4;
    const int a_row = tid >> 1;
    const int a_col = (tid & 1) * 4;
    const int b_row = tid >> 5;
    const int b_col = (tid & 31) * 4;

    float acc[8][8];
#pragma unroll
    for (int i = 0; i < 8; ++i)
#pragma unroll
        for (int j = 0; j < 8; ++j) acc[i][j] = 0.f;

    const int kmax = q0 + 128;
    for (int k0 = 0; k0 < kmax; k0 += 8) {
        const float4 sv = *(const float4*)(Sb + (size_t)(q0 + a_row) * Tt + k0 + a_col);
        const float4 vv = *(const float4*)(Vb + (size_t)(k0 + b_row) * Dd + d0 + b_col);
        float wv[4];
        {
            const float sarr[4] = {sv.x, sv.y, sv.z, sv.w};
#pragma unroll
            for (int i = 0; i < 4; ++i) {
                const int jg = k0 + a_col + i;
                wv[i] = __expf(sarr[i] - mb[jg]) * lb[jg];
            }
        }
        __syncthreads();
        As[a_col + 0][a_row] = wv[0];
        As[a_col + 1][a_row] = wv[1];
        As[a_col + 2][a_row] = wv[2];
        As[a_col + 3][a_row] = wv[3];
        *(float4*)&Bs[b_row][b_col] = vv;
        __syncthreads();
#pragma unroll
        for (int kk = 0; kk < 8; ++kk) {
            const float4 a0 = *(const float4*)&As[kk][ty * 8];
            const float4 a1 = *(const float4*)&As[kk][ty * 8 + 4];
            const float4 b0 = *(const float4*)&Bs[kk][tx * 4];
            const float4 b1 = *(const float4*)&Bs[kk][64 + tx * 4];
            const float a[8] = {a0.x, a0.y, a0.z, a0.w, a1.x, a1.y, a1.z, a1.w};
            const float bb[8] = {b0.x, b0.y, b0.z, b0.w, b1.x, b1.y, b1.z, b1.w};
#pragma unroll
            for (int i = 0; i < 8; ++i)
#pragma unroll
                for (int j = 0; j < 8; ++j)
                    acc[i][j] = fmaf(a[i], bb[j], acc[i][j]);
        }
    }
#pragma unroll
    for (int i = 0; i < 8; ++i) {
        float* dst = Ob + (size_t)(q0 + ty * 8 + i) * Dd + d0;
        *(float4*)(dst + tx * 4) = make_float4(acc[i][0], acc[i][1], acc[i][2], acc[i][3]);
        *(float4*)(dst + 64 + tx * 4) = make_float4(acc[i][4], acc[i][5], acc[i][6], acc[i][7]);
    }
}

}  // namespace

extern "C" void kernel_launch(void* const* d_in, const int* in_sizes, int n_in,
                              void* d_out, int out_size, void* d_ws, size_t ws_size,
                              hipStream_t stream)
{
    const float* X  = (const float*)d_in[0];
    const float* Wq = (const float*)d_in[1];
    const float* Wk = (const float*)d_in[2];
    const float* Wv = (const float*)d_in[3];

    // workspace layout:
    //  region0 (64 MB): [Xhi 16|Xlo 16|Whit 6|Wlot 6] then overlaid by S (64)
    //  then: V fp32 (32) | Qhi,Qlo,Khi,Klo (16 each) | Mb,Lb,Pm,Pl (~2.1)
    char* ws = (char*)d_ws;
    ushort* Xhi  = (ushort*)ws;
    ushort* Xlo  = Xhi + (size_t)BT * Dd;
    ushort* Whit = Xlo + (size_t)BT * Dd;
    ushort* Wlot = Whit + (size_t)3 * Dd * Dd;
    float*  S    = (float*)ws;                       // overlays the above
    char* p = ws + (size_t)64 * 1024 * 1024;
    float*  Vf  = (float*)p;
    ushort* Qhi = (ushort*)(p + (size_t)32 * 1024 * 1024);
    ushort* Qlo = Qhi + (size_t)BT * Dd;
    ushort* Khi = Qlo + (size_t)BT * Dd;
    ushort* Klo = Khi + (size_t)BT * Dd;
    float*  Mb  = (float*)(Klo + (size_t)BT * Dd);
    float*  Lb  = Mb + (size_t)Bb * Tt;
    float*  Pm  = Lb + (size_t)Bb * Tt;
    float*  Pl  = Pm + (size_t)Bb * NCH * Tt;
    float*  Out = (float*)d_out;

    convert_x_kernel<<<BT * Dd / 1024, 256, 0, stream>>>(X, Xhi, Xlo);
    convert_w_kernel<<<dim3(16, 16, 3), 256, 0, stream>>>(Wq, Wk, Wv, Whit, Wlot);
    qkv_mfma_kernel<<<dim3(24, 64), 256, 0, stream>>>(Xhi, Xlo, Whit, Wlot,
                                                      Qhi, Qlo, Khi, Klo, Vf);
    scores_mfma_kernel<<<dim3(16, 16, Bb), 256, 0, stream>>>(Qhi, Qlo, Khi, Klo, S);
    colstats_part_kernel<<<dim3(Tt / 256, NCH, Bb), 256, 0, stream>>>(S, Pm, Pl);
    colstats_merge_kernel<<<dim3(Tt / 256, Bb), 256, 0, stream>>>(Pm, Pl, Mb, Lb);
    context_kernel<<<dim3(Dd / 128, Tt / 128, Bb), 256, 0, stream>>>(S, Vf, Mb, Lb, Out);
}

// Round 4
// 697.878 us; speedup vs baseline: 2.8644x; 1.7816x over previous
//
#include <hip/hip_runtime.h>
#include <math.h>

typedef _Float16 half4 __attribute__((ext_vector_type(4)));
typedef _Float16 half8 __attribute__((ext_vector_type(8)));
typedef float f32x4 __attribute__((ext_vector_type(4)));

namespace {

constexpr int Bb = 4;
constexpr int Tt = 2048;
constexpr int Dd = 1024;
constexpr int BT = Bb * Tt;   // 8192

// ---- fp32 -> 2x fp16 split (RNE): hi+lo carries ~22 mantissa bits ----
__device__ inline _Float16 f2h(float f) { return (_Float16)f; }

// ---------------------------------------------------------------------------
// convert X: fp32 [BT][D] -> Xhi, Xlo fp16
// ---------------------------------------------------------------------------
__global__ __launch_bounds__(256) void convert_x_kernel(
    const float* __restrict__ X, _Float16* __restrict__ Xhi, _Float16* __restrict__ Xlo)
{
    const int idx = (blockIdx.x * 256 + threadIdx.x) * 4;
    const float4 v = *(const float4*)(X + idx);
    const float a[4] = {v.x, v.y, v.z, v.w};
    half4 h, l;
#pragma unroll
    for (int i = 0; i < 4; ++i) {
        h[i] = f2h(a[i]);
        l[i] = f2h(a[i] - (float)h[i]);
    }
    *(half4*)(Xhi + idx) = h;
    *(half4*)(Xlo + idx) = l;
}

// ---------------------------------------------------------------------------
// convert+transpose W: fp32 W[k][n] -> Whit[n][k], Wlot[n][k] fp16 (3 mats)
// ---------------------------------------------------------------------------
__global__ __launch_bounds__(256) void convert_w_kernel(
    const float* __restrict__ W0, const float* __restrict__ W1,
    const float* __restrict__ W2,
    _Float16* __restrict__ Whit, _Float16* __restrict__ Wlot)
{
    const int mat = blockIdx.z;
    const float* W = (mat == 0) ? W0 : (mat == 1) ? W1 : W2;
    _Float16* Ht = Whit + (size_t)mat * Dd * Dd;
    _Float16* Lt = Wlot + (size_t)mat * Dd * Dd;
    __shared__ float tile[64][65];
    const int n0 = blockIdx.x * 64, k0 = blockIdx.y * 64;
    const int tx = threadIdx.x & 63, ty = threadIdx.x >> 6;
#pragma unroll
    for (int i = 0; i < 16; ++i)
        tile[ty + i * 4][tx] = W[(size_t)(k0 + ty + i * 4) * Dd + n0 + tx];
    __syncthreads();
#pragma unroll
    for (int i = 0; i < 16; ++i) {
        const float v = tile[tx][ty + i * 4];           // = W[k0+tx][n0+ty+i*4]
        const size_t o = (size_t)(n0 + ty + i * 4) * Dd + k0 + tx;
        const _Float16 h = f2h(v);
        Ht[o] = h;
        Lt[o] = f2h(v - (float)h);
    }
}

// ---------------------------------------------------------------------------
// MFMA GEMM template: 128x128 tile, 4 waves x (4x4) 16x16x32_f16 tiles.
// LDS fragment-blocked (16B/lane), staged by global_load_lds width=16.
// 3 passes: (hi,hi),(hi,lo),(lo,hi) -- lo.lo dropped (error ~2^-24 rel).
// ---------------------------------------------------------------------------

// Kernel 1: QKV.  mats 0,1 -> Q/K fp16 hi/lo; mat 2 -> V fp16 row-major.
__global__ __launch_bounds__(256) void qkv_mfma_kernel(
    const _Float16* __restrict__ Xhi, const _Float16* __restrict__ Xlo,
    const _Float16* __restrict__ Whit, const _Float16* __restrict__ Wlot,
    _Float16* __restrict__ Qhi, _Float16* __restrict__ Qlo,
    _Float16* __restrict__ Khi, _Float16* __restrict__ Klo,
    _Float16* __restrict__ Vrow)
{
    __shared__ _Float16 Al[8][512];
    __shared__ _Float16 Bl[8][512];

    const int mat = blockIdx.x >> 3;
    const int n0 = (blockIdx.x & 7) * 128;
    const int m0 = blockIdx.y * 128;
    const _Float16* WhT = Whit + (size_t)mat * Dd * Dd;
    const _Float16* WlT = Wlot + (size_t)mat * Dd * Dd;

    const int tid = threadIdx.x;
    const int w = tid >> 6, lane = tid & 63;
    const int lr = lane & 15, lq = lane >> 4;
    const int wr = (w >> 1) * 4, wc = (w & 1) * 4;

    f32x4 acc[4][4];
#pragma unroll
    for (int i = 0; i < 4; ++i)
#pragma unroll
        for (int j = 0; j < 4; ++j)
#pragma unroll
            for (int c = 0; c < 4; ++c) acc[i][j][c] = 0.f;

    const _Float16* APs[3] = {Xhi, Xhi, Xlo};
    const _Float16* BPs[3] = {WhT, WlT, WhT};
    for (int pass = 0; pass < 3; ++pass) {
        const _Float16* Ap = APs[pass];
        const _Float16* Bp = BPs[pass];
        for (int kk = 0; kk < 1024; kk += 32) {
            __syncthreads();
#pragma unroll
            for (int s2 = 0; s2 < 2; ++s2) {
                const int s = w * 2 + s2;
                const _Float16* ga = Ap + (size_t)(m0 + s * 16 + lr) * Dd + kk + lq * 8;
                const _Float16* gb = Bp + (size_t)(n0 + s * 16 + lr) * Dd + kk + lq * 8;
                __builtin_amdgcn_global_load_lds(
                    (const __attribute__((address_space(1))) unsigned int*)ga,
                    (__attribute__((address_space(3))) unsigned int*)&Al[s][0], 16, 0, 0);
                __builtin_amdgcn_global_load_lds(
                    (const __attribute__((address_space(1))) unsigned int*)gb,
                    (__attribute__((address_space(3))) unsigned int*)&Bl[s][0], 16, 0, 0);
            }
            __syncthreads();
            half8 a[4], b[4];
#pragma unroll
            for (int i = 0; i < 4; ++i) a[i] = *(const half8*)&Al[wr + i][lane * 8];
#pragma unroll
            for (int j = 0; j < 4; ++j) b[j] = *(const half8*)&Bl[wc + j][lane * 8];
#pragma unroll
            for (int i = 0; i < 4; ++i)
#pragma unroll
                for (int j = 0; j < 4; ++j)
                    acc[i][j] = __builtin_amdgcn_mfma_f32_16x16x32_f16(a[i], b[j], acc[i][j], 0, 0, 0);
        }
    }

    // epilogue: C[row = m0+(wr+i)*16+lq*4+r][col = n0+(wc+j)*16+lr]
    if (mat < 2) {
        _Float16* Hh = mat ? Khi : Qhi;
        _Float16* Ll = mat ? Klo : Qlo;
#pragma unroll
        for (int i = 0; i < 4; ++i)
#pragma unroll
            for (int r = 0; r < 4; ++r) {
                const int row = m0 + (wr + i) * 16 + lq * 4 + r;
#pragma unroll
                for (int j = 0; j < 4; ++j) {
                    const int col = n0 + (wc + j) * 16 + lr;
                    const float v = acc[i][j][r];
                    const _Float16 h = f2h(v);
                    Hh[(size_t)row * Dd + col] = h;
                    Ll[(size_t)row * Dd + col] = f2h(v - (float)h);
                }
            }
    } else {
#pragma unroll
        for (int i = 0; i < 4; ++i)
#pragma unroll
            for (int r = 0; r < 4; ++r) {
                const int row = m0 + (wr + i) * 16 + lq * 4 + r;
#pragma unroll
                for (int j = 0; j < 4; ++j) {
                    const int col = n0 + (wc + j) * 16 + lr;
                    Vrow[(size_t)row * Dd + col] = f2h(acc[i][j][r]);
                }
            }
    }
}

// ---------------------------------------------------------------------------
// transpose V: fp16 [b][t][d] -> Vt [b][d][t]  (context B-operand layout)
// ---------------------------------------------------------------------------
__global__ __launch_bounds__(256) void transpose_v_kernel(
    const _Float16* __restrict__ Vrow, _Float16* __restrict__ Vt)
{
    __shared__ _Float16 tile[64][78];   // 78: odd word stride -> conflict-free
    const int d0 = blockIdx.x * 64, t0 = blockIdx.y * 64, b = blockIdx.z;
    const int tx = threadIdx.x & 63, ty = threadIdx.x >> 6;
#pragma unroll
    for (int i = 0; i < 16; ++i)
        tile[ty + i * 4][tx] = Vrow[((size_t)b * Tt + t0 + ty + i * 4) * Dd + d0 + tx];
    __syncthreads();
#pragma unroll
    for (int i = 0; i < 16; ++i)
        Vt[(size_t)b * Dd * Tt + (size_t)(d0 + ty + i * 4) * Tt + t0 + tx] = tile[tx][ty + i * 4];
}

// ---------------------------------------------------------------------------
// Kernel 2: scores.  Only lower-triangle tiles stored; upper tiles never
// written (consumers use tile predicates).  Diagonal tiles store -inf for j>q.
// ---------------------------------------------------------------------------
__global__ __launch_bounds__(256) void scores_mfma_kernel(
    const _Float16* __restrict__ Qhi, const _Float16* __restrict__ Qlo,
    const _Float16* __restrict__ Khi, const _Float16* __restrict__ Klo,
    float* __restrict__ S)
{
    const int bxi = blockIdx.x, byi = blockIdx.y, b = blockIdx.z;
    if (bxi > byi) return;              // fully masked tile: not materialized
    const int j0 = bxi * 128, q0 = byi * 128;
    float* Sb = S + (size_t)b * Tt * Tt;

    __shared__ _Float16 Al[8][512];
    __shared__ _Float16 Bl[8][512];
    const _Float16* Qh = Qhi + (size_t)b * Tt * Dd;
    const _Float16* Ql = Qlo + (size_t)b * Tt * Dd;
    const _Float16* Kh = Khi + (size_t)b * Tt * Dd;
    const _Float16* Kl = Klo + (size_t)b * Tt * Dd;

    const int tid = threadIdx.x;
    const int w = tid >> 6, lane = tid & 63;
    const int lr = lane & 15, lq = lane >> 4;
    const int wr = (w >> 1) * 4, wc = (w & 1) * 4;

    f32x4 acc[4][4];
#pragma unroll
    for (int i = 0; i < 4; ++i)
#pragma unroll
        for (int j = 0; j < 4; ++j)
#pragma unroll
            for (int c = 0; c < 4; ++c) acc[i][j][c] = 0.f;

    const _Float16* APs[3] = {Qh, Qh, Ql};
    const _Float16* BPs[3] = {Kh, Kl, Kh};
    for (int pass = 0; pass < 3; ++pass) {
        const _Float16* Ap = APs[pass];
        const _Float16* Bp = BPs[pass];
        for (int kk = 0; kk < 1024; kk += 32) {
            __syncthreads();
#pragma unroll
            for (int s2 = 0; s2 < 2; ++s2) {
                const int s = w * 2 + s2;
                const _Float16* ga = Ap + (size_t)(q0 + s * 16 + lr) * Dd + kk + lq * 8;
                const _Float16* gb = Bp + (size_t)(j0 + s * 16 + lr) * Dd + kk + lq * 8;
                __builtin_amdgcn_global_load_lds(
                    (const __attribute__((address_space(1))) unsigned int*)ga,
                    (__attribute__((address_space(3))) unsigned int*)&Al[s][0], 16, 0, 0);
                __builtin_amdgcn_global_load_lds(
                    (const __attribute__((address_space(1))) unsigned int*)gb,
                    (__attribute__((address_space(3))) unsigned int*)&Bl[s][0], 16, 0, 0);
            }
            __syncthreads();
            half8 a[4], b2[4];
#pragma unroll
            for (int i = 0; i < 4; ++i) a[i] = *(const half8*)&Al[wr + i][lane * 8];
#pragma unroll
            for (int j = 0; j < 4; ++j) b2[j] = *(const half8*)&Bl[wc + j][lane * 8];
#pragma unroll
            for (int i = 0; i < 4; ++i)
#pragma unroll
                for (int j = 0; j < 4; ++j)
                    acc[i][j] = __builtin_amdgcn_mfma_f32_16x16x32_f16(a[i], b2[j], acc[i][j], 0, 0, 0);
        }
    }

#pragma unroll
    for (int i = 0; i < 4; ++i)
#pragma unroll
        for (int r = 0; r < 4; ++r) {
            const int q = q0 + (wr + i) * 16 + lq * 4 + r;
#pragma unroll
            for (int j = 0; j < 4; ++j) {
                const int jg = j0 + (wc + j) * 16 + lr;
                Sb[(size_t)q * Tt + jg] =
                    (jg <= q) ? floorf(acc[i][j][r] * 0.03125f) : -INFINITY;
            }
        }
}

// ---------------------------------------------------------------------------
// colstats (softmax over the QUERY axis): two-phase, tile-predicated reads
// ---------------------------------------------------------------------------
constexpr int QCH = 64;
constexpr int NCH = Tt / QCH;   // 32

__global__ __launch_bounds__(256) void colstats_part_kernel(
    const float* __restrict__ S, float* __restrict__ Pm, float* __restrict__ Pl)
{
    const int jb = blockIdx.x, qc = blockIdx.y, b = blockIdx.z;
    const int j = jb * 256 + threadIdx.x;
    const int r0 = qc * QCH;
    const size_t pidx = ((size_t)b * NCH + qc) * Tt + j;
    const int jt = j >> 7;           // wave-uniform (wave spans 64 cols)
    const int qt = qc >> 1;          // chunk lies inside one q-tile
    if (jt > qt) { Pm[pidx] = -INFINITY; Pl[pidx] = 0.f; return; }
    const float* Sb = S + (size_t)b * Tt * Tt;
    float m = -INFINITY, l = 0.f;
    for (int q = r0; q < r0 + QCH; ++q) {
        const float s = Sb[(size_t)q * Tt + j];
        if (s != -INFINITY) {
            if (s > m) { l *= __expf(m - s); m = s; }
            l += __expf(s - m);
        }
    }
    Pm[pidx] = m;
    Pl[pidx] = l;
}

__global__ __launch_bounds__(256) void colstats_merge_kernel(
    const float* __restrict__ Pm, const float* __restrict__ Pl,
    float* __restrict__ Mb, float* __restrict__ Lb)
{
    const int j = blockIdx.x * 256 + threadIdx.x;
    const int b = blockIdx.y;
    float m = -INFINITY, l = 0.f;
#pragma unroll 4
    for (int c = 0; c < NCH; ++c) {
        const size_t pidx = ((size_t)b * NCH + c) * Tt + j;
        const float mi = Pm[pidx];
        if (mi == -INFINITY) continue;
        const float li = Pl[pidx];
        if (mi > m) { l = l * __expf(m - mi) + li; m = mi; }
        else        { l += li * __expf(mi - m); }
    }
    Mb[(size_t)b * Tt + j] = m;
    Lb[(size_t)b * Tt + j] = (l > 0.f) ? 1.f / l : 0.f;
}

// ---------------------------------------------------------------------------
// P = exp(S - m[k]) * invl[k] as fp16, zeros above the diagonal.
// ---------------------------------------------------------------------------
__global__ __launch_bounds__(256) void pmat_kernel(
    const float* __restrict__ S, const float* __restrict__ Mb,
    const float* __restrict__ Lb, _Float16* __restrict__ P)
{
    const size_t gid = ((size_t)blockIdx.x * 256 + threadIdx.x) * 8;
    const int b = (int)(gid >> 22);
    const int rem = (int)(gid & ((1u << 22) - 1));
    const int q = rem >> 11;
    const int k0 = rem & 2047;
    half8 out = {0, 0, 0, 0, 0, 0, 0, 0};
    if ((k0 >> 7) <= (q >> 7)) {   // tile written
        const float* Sp = S + (size_t)b * Tt * Tt + (size_t)q * Tt + k0;
        const float* mp = Mb + (size_t)b * Tt + k0;
        const float* lp = Lb + (size_t)b * Tt + k0;
#pragma unroll
        for (int i = 0; i < 8; ++i)
            out[i] = f2h(__expf(Sp[i] - mp[i]) * lp[i]);
    }
    *(half8*)(P + gid) = out;
}

// ---------------------------------------------------------------------------
// Kernel 3: context = P @ V.  Single-pass fp16 MFMA, causal k-truncation.
// A = P[b][q][k] (k contig), B = Vt[b][d][t] (t contig). Output fp32.
// ---------------------------------------------------------------------------
__global__ __launch_bounds__(256) void context_mfma_kernel(
    const _Float16* __restrict__ P, const _Float16* __restrict__ Vt,
    float* __restrict__ Out)
{
    __shared__ _Float16 Al[8][512];
    __shared__ _Float16 Bl[8][512];

    const int bx = blockIdx.x;                       // 8 d-blocks
    const int by = (int)gridDim.y - 1 - blockIdx.y;  // heavy q-blocks first
    const int b  = blockIdx.z;
    const int d0 = bx * 128;
    const int q0 = by * 128;
    const _Float16* Pb = P + (size_t)b * Tt * Tt;
    const _Float16* Vb = Vt + (size_t)b * Dd * Tt;
    float* Ob = Out + (size_t)b * Tt * Dd;

    const int tid = threadIdx.x;
    const int w = tid >> 6, lane = tid & 63;
    const int lr = lane & 15, lq = lane >> 4;
    const int wr = (w >> 1) * 4, wc = (w & 1) * 4;

    f32x4 acc[4][4];
#pragma unroll
    for (int i = 0; i < 4; ++i)
#pragma unroll
        for (int j = 0; j < 4; ++j)
#pragma unroll
            for (int c = 0; c < 4; ++c) acc[i][j][c] = 0.f;

    const int kmax = q0 + 128;   // P is zero for k > q
    for (int k0 = 0; k0 < kmax; k0 += 32) {
        __syncthreads();
#pragma unroll
        for (int s2 = 0; s2 < 2; ++s2) {
            const int s = w * 2 + s2;
            const _Float16* ga = Pb + (size_t)(q0 + s * 16 + lr) * Tt + k0 + lq * 8;
            const _Float16* gb = Vb + (size_t)(d0 + s * 16 + lr) * Tt + k0 + lq * 8;
            __builtin_amdgcn_global_load_lds(
                (const __attribute__((address_space(1))) unsigned int*)ga,
                (__attribute__((address_space(3))) unsigned int*)&Al[s][0], 16, 0, 0);
            __builtin_amdgcn_global_load_lds(
                (const __attribute__((address_space(1))) unsigned int*)gb,
                (__attribute__((address_space(3))) unsigned int*)&Bl[s][0], 16, 0, 0);
        }
        __syncthreads();
        half8 a[4], b2[4];
#pragma unroll
        for (int i = 0; i < 4; ++i) a[i] = *(const half8*)&Al[wr + i][lane * 8];
#pragma unroll
        for (int j = 0; j < 4; ++j) b2[j] = *(const half8*)&Bl[wc + j][lane * 8];
#pragma unroll
        for (int i = 0; i < 4; ++i)
#pragma unroll
            for (int j = 0; j < 4; ++j)
                acc[i][j] = __builtin_amdgcn_mfma_f32_16x16x32_f16(a[i], b2[j], acc[i][j], 0, 0, 0);
    }

#pragma unroll
    for (int i = 0; i < 4; ++i)
#pragma unroll
        for (int r = 0; r < 4; ++r) {
            const int row = q0 + (wr + i) * 16 + lq * 4 + r;
#pragma unroll
            for (int j = 0; j < 4; ++j) {
                const int col = d0 + (wc + j) * 16 + lr;
                Ob[(size_t)row * Dd + col] = acc[i][j][r];
            }
        }
}

}  // namespace

extern "C" void kernel_launch(void* const* d_in, const int* in_sizes, int n_in,
                              void* d_out, int out_size, void* d_ws, size_t ws_size,
                              hipStream_t stream)
{
    const float* X  = (const float*)d_in[0];
    const float* Wq = (const float*)d_in[1];
    const float* Wk = (const float*)d_in[2];
    const float* Wv = (const float*)d_in[3];

    // workspace:
    //  [0,64MB):   Xhi|Xlo|Whit|Wlot (44MB)  -- overlaid by S fp32 (64MB)
    //  [64,96MB):  Vrow fp16 (16) | Vt fp16 (16)
    //  [96,160MB): Qhi|Qlo|Khi|Klo fp16 (16 each) -- Qhi+Qlo overlaid by P (32)
    //  [160MB..):  Mb | Lb | Pm | Pl  (~2.2MB)
    char* ws = (char*)d_ws;
    _Float16* Xhi  = (_Float16*)ws;
    _Float16* Xlo  = Xhi + (size_t)BT * Dd;
    _Float16* Whit = Xlo + (size_t)BT * Dd;
    _Float16* Wlot = Whit + (size_t)3 * Dd * Dd;
    float*    S    = (float*)ws;                       // overlay
    char* p1 = ws + (size_t)64 * 1024 * 1024;
    _Float16* Vrow = (_Float16*)p1;
    _Float16* Vt   = Vrow + (size_t)BT * Dd;
    char* p2 = p1 + (size_t)32 * 1024 * 1024;
    _Float16* Qhi = (_Float16*)p2;
    _Float16* Qlo = Qhi + (size_t)BT * Dd;
    _Float16* Khi = Qlo + (size_t)BT * Dd;
    _Float16* Klo = Khi + (size_t)BT * Dd;
    _Float16* P   = Qhi;                               // overlay after scores
    float*    Mb  = (float*)(Klo + (size_t)BT * Dd);
    float*    Lb  = Mb + (size_t)Bb * Tt;
    float*    Pm  = Lb + (size_t)Bb * Tt;
    float*    Pl  = Pm + (size_t)Bb * NCH * Tt;
    float*    Out = (float*)d_out;

    convert_x_kernel<<<BT * Dd / 1024, 256, 0, stream>>>(X, Xhi, Xlo);
    convert_w_kernel<<<dim3(16, 16, 3), 256, 0, stream>>>(Wq, Wk, Wv, Whit, Wlot);
    qkv_mfma_kernel<<<dim3(24, 64), 256, 0, stream>>>(Xhi, Xlo, Whit, Wlot,
                                                      Qhi, Qlo, Khi, Klo, Vrow);
    transpose_v_kernel<<<dim3(Dd / 64, Tt / 64, Bb), 256, 0, stream>>>(Vrow, Vt);
    scores_mfma_kernel<<<dim3(16, 16, Bb), 256, 0, stream>>>(Qhi, Qlo, Khi, Klo, S);
    colstats_part_kernel<<<dim3(Tt / 256, NCH, Bb), 256, 0, stream>>>(S, Pm, Pl);
    colstats_merge_kernel<<<dim3(Tt / 256, Bb), 256, 0, stream>>>(Pm, Pl, Mb, Lb);
    pmat_kernel<<<(int)(((size_t)Bb * Tt * Tt / 8) / 256), 256, 0, stream>>>(S, Mb, Lb, P);
    context_mfma_kernel<<<dim3(Dd / 128, Tt / 128, Bb), 256, 0, stream>>>(P, Vt, Out);
}

// Round 5
// 541.452 us; speedup vs baseline: 3.6920x; 1.2889x over previous
//
#include <hip/hip_runtime.h>
#include <math.h>

typedef _Float16 half4 __attribute__((ext_vector_type(4)));
typedef _Float16 half8 __attribute__((ext_vector_type(8)));
typedef float f32x4 __attribute__((ext_vector_type(4)));

#define GLD16(gptr, lptr)                                                     \
    __builtin_amdgcn_global_load_lds(                                         \
        (const __attribute__((address_space(1))) unsigned int*)(gptr),        \
        (__attribute__((address_space(3))) unsigned int*)(lptr), 16, 0, 0)

namespace {

constexpr int Bb = 4;
constexpr int Tt = 2048;
constexpr int Dd = 1024;
constexpr int BT = Bb * Tt;   // 8192

__device__ inline _Float16 f2h(float f) { return (_Float16)f; }

// ---------------------------------------------------------------------------
// convert X: fp32 [BT][D] -> Xhi, Xlo fp16
// ---------------------------------------------------------------------------
__global__ __launch_bounds__(256) void convert_x_kernel(
    const float* __restrict__ X, _Float16* __restrict__ Xhi, _Float16* __restrict__ Xlo)
{
    const int idx = (blockIdx.x * 256 + threadIdx.x) * 4;
    const float4 v = *(const float4*)(X + idx);
    const float a[4] = {v.x, v.y, v.z, v.w};
    half4 h, l;
#pragma unroll
    for (int i = 0; i < 4; ++i) {
        h[i] = f2h(a[i]);
        l[i] = f2h(a[i] - (float)h[i]);
    }
    *(half4*)(Xhi + idx) = h;
    *(half4*)(Xlo + idx) = l;
}

// ---------------------------------------------------------------------------
// convert+transpose W: fp32 W[k][n] -> Whit[n][k], Wlot[n][k] fp16 (3 mats)
// ---------------------------------------------------------------------------
__global__ __launch_bounds__(256) void convert_w_kernel(
    const float* __restrict__ W0, const float* __restrict__ W1,
    const float* __restrict__ W2,
    _Float16* __restrict__ Whit, _Float16* __restrict__ Wlot)
{
    const int mat = blockIdx.z;
    const float* W = (mat == 0) ? W0 : (mat == 1) ? W1 : W2;
    _Float16* Ht = Whit + (size_t)mat * Dd * Dd;
    _Float16* Lt = Wlot + (size_t)mat * Dd * Dd;
    __shared__ float tile[64][65];
    const int n0 = blockIdx.x * 64, k0 = blockIdx.y * 64;
    const int tx = threadIdx.x & 63, ty = threadIdx.x >> 6;
#pragma unroll
    for (int i = 0; i < 16; ++i)
        tile[ty + i * 4][tx] = W[(size_t)(k0 + ty + i * 4) * Dd + n0 + tx];
    __syncthreads();
#pragma unroll
    for (int i = 0; i < 16; ++i) {
        const float v = tile[tx][ty + i * 4];
        const size_t o = (size_t)(n0 + ty + i * 4) * Dd + k0 + tx;
        const _Float16 h = f2h(v);
        Ht[o] = h;
        Lt[o] = f2h(v - (float)h);
    }
}

// ---------------------------------------------------------------------------
// Split GEMM core: 128x128 tile, 4 waves x (4x4) 16x16x32_f16.
// Multi-product K-loop: stage Ahi,Alo,Bhi,Blo once per 32-k chunk (32 KB LDS),
// then 48 MFMAs (hi.hi + hi.lo + lo.hi) per barrier window.
// ---------------------------------------------------------------------------

// Kernel 1: QKV.  mats 0,1 -> Q/K fp16 hi/lo; mat 2 -> V fp16 row-major.
__global__ __launch_bounds__(256) void qkv_mfma_kernel(
    const _Float16* __restrict__ Xhi, const _Float16* __restrict__ Xlo,
    const _Float16* __restrict__ Whit, const _Float16* __restrict__ Wlot,
    _Float16* __restrict__ Qhi, _Float16* __restrict__ Qlo,
    _Float16* __restrict__ Khi, _Float16* __restrict__ Klo,
    _Float16* __restrict__ Vrow)
{
    __shared__ _Float16 Ahl[2][8][512];
    __shared__ _Float16 Bhl[2][8][512];

    const int mat = blockIdx.x >> 3;
    const int n0 = (blockIdx.x & 7) * 128;
    const int m0 = blockIdx.y * 128;
    const _Float16* WhT = Whit + (size_t)mat * Dd * Dd;
    const _Float16* WlT = Wlot + (size_t)mat * Dd * Dd;

    const int tid = threadIdx.x;
    const int w = tid >> 6, lane = tid & 63;
    const int lr = lane & 15, lq = lane >> 4;
    const int wr = (w >> 1) * 4, wc = (w & 1) * 4;

    f32x4 acc[4][4];
#pragma unroll
    for (int i = 0; i < 4; ++i)
#pragma unroll
        for (int j = 0; j < 4; ++j)
#pragma unroll
            for (int c = 0; c < 4; ++c) acc[i][j][c] = 0.f;

    for (int kk = 0; kk < 1024; kk += 32) {
        __syncthreads();
#pragma unroll
        for (int s2 = 0; s2 < 2; ++s2) {
            const int s = w * 2 + s2;
            const size_t ar = (size_t)(m0 + s * 16 + lr) * Dd + kk + lq * 8;
            const size_t br = (size_t)(n0 + s * 16 + lr) * Dd + kk + lq * 8;
            GLD16(Xhi + ar, &Ahl[0][s][0]);
            GLD16(Xlo + ar, &Ahl[1][s][0]);
            GLD16(WhT + br, &Bhl[0][s][0]);
            GLD16(WlT + br, &Bhl[1][s][0]);
        }
        __syncthreads();
        half8 ah[4], al[4], bh[4], bl[4];
#pragma unroll
        for (int i = 0; i < 4; ++i) {
            ah[i] = *(const half8*)&Ahl[0][wr + i][lane * 8];
            al[i] = *(const half8*)&Ahl[1][wr + i][lane * 8];
        }
#pragma unroll
        for (int j = 0; j < 4; ++j) {
            bh[j] = *(const half8*)&Bhl[0][wc + j][lane * 8];
            bl[j] = *(const half8*)&Bhl[1][wc + j][lane * 8];
        }
#pragma unroll
        for (int i = 0; i < 4; ++i)
#pragma unroll
            for (int j = 0; j < 4; ++j) {
                acc[i][j] = __builtin_amdgcn_mfma_f32_16x16x32_f16(ah[i], bh[j], acc[i][j], 0, 0, 0);
                acc[i][j] = __builtin_amdgcn_mfma_f32_16x16x32_f16(ah[i], bl[j], acc[i][j], 0, 0, 0);
                acc[i][j] = __builtin_amdgcn_mfma_f32_16x16x32_f16(al[i], bh[j], acc[i][j], 0, 0, 0);
            }
    }

    // epilogue: C[row = m0+(wr+i)*16+lq*4+r][col = n0+(wc+j)*16+lr]
    if (mat < 2) {
        _Float16* Hh = mat ? Khi : Qhi;
        _Float16* Ll = mat ? Klo : Qlo;
#pragma unroll
        for (int i = 0; i < 4; ++i)
#pragma unroll
            for (int r = 0; r < 4; ++r) {
                const int row = m0 + (wr + i) * 16 + lq * 4 + r;
#pragma unroll
                for (int j = 0; j < 4; ++j) {
                    const int col = n0 + (wc + j) * 16 + lr;
                    const float v = acc[i][j][r];
                    const _Float16 h = f2h(v);
                    Hh[(size_t)row * Dd + col] = h;
                    Ll[(size_t)row * Dd + col] = f2h(v - (float)h);
                }
            }
    } else {
#pragma unroll
        for (int i = 0; i < 4; ++i)
#pragma unroll
            for (int r = 0; r < 4; ++r) {
                const int row = m0 + (wr + i) * 16 + lq * 4 + r;
#pragma unroll
                for (int j = 0; j < 4; ++j) {
                    const int col = n0 + (wc + j) * 16 + lr;
                    Vrow[(size_t)row * Dd + col] = f2h(acc[i][j][r]);
                }
            }
    }
}

// ---------------------------------------------------------------------------
// transpose V: fp16 [b][t][d] -> Vt [b][d][t]
// ---------------------------------------------------------------------------
__global__ __launch_bounds__(256) void transpose_v_kernel(
    const _Float16* __restrict__ Vrow, _Float16* __restrict__ Vt)
{
    __shared__ _Float16 tile[64][78];
    const int d0 = blockIdx.x * 64, t0 = blockIdx.y * 64, b = blockIdx.z;
    const int tx = threadIdx.x & 63, ty = threadIdx.x >> 6;
#pragma unroll
    for (int i = 0; i < 16; ++i)
        tile[ty + i * 4][tx] = Vrow[((size_t)b * Tt + t0 + ty + i * 4) * Dd + d0 + tx];
    __syncthreads();
#pragma unroll
    for (int i = 0; i < 16; ++i)
        Vt[(size_t)b * Dd * Tt + (size_t)(d0 + ty + i * 4) * Tt + t0 + tx] = tile[tx][ty + i * 4];
}

// ---------------------------------------------------------------------------
// Kernel 2: scores, compact lower-triangle grid (136 tiles x Bb).
// ---------------------------------------------------------------------------
__global__ __launch_bounds__(256) void scores_mfma_kernel(
    const _Float16* __restrict__ Qhi, const _Float16* __restrict__ Qlo,
    const _Float16* __restrict__ Khi, const _Float16* __restrict__ Klo,
    float* __restrict__ S)
{
    // triangular decode: t -> (byi, bxi), byi >= bxi
    const int t = blockIdx.x;
    int byi = (int)((sqrtf(8.f * t + 1.f) - 1.f) * 0.5f);
    if ((byi + 1) * (byi + 2) / 2 <= t) ++byi;
    if (byi * (byi + 1) / 2 > t) --byi;
    const int bxi = t - byi * (byi + 1) / 2;
    const int b = blockIdx.z;
    const int j0 = bxi * 128, q0 = byi * 128;
    float* Sb = S + (size_t)b * Tt * Tt;

    __shared__ _Float16 Ahl[2][8][512];
    __shared__ _Float16 Bhl[2][8][512];
    const _Float16* Qh = Qhi + (size_t)b * Tt * Dd;
    const _Float16* Ql = Qlo + (size_t)b * Tt * Dd;
    const _Float16* Kh = Khi + (size_t)b * Tt * Dd;
    const _Float16* Kl = Klo + (size_t)b * Tt * Dd;

    const int tid = threadIdx.x;
    const int w = tid >> 6, lane = tid & 63;
    const int lr = lane & 15, lq = lane >> 4;
    const int wr = (w >> 1) * 4, wc = (w & 1) * 4;

    f32x4 acc[4][4];
#pragma unroll
    for (int i = 0; i < 4; ++i)
#pragma unroll
        for (int j = 0; j < 4; ++j)
#pragma unroll
            for (int c = 0; c < 4; ++c) acc[i][j][c] = 0.f;

    for (int kk = 0; kk < 1024; kk += 32) {
        __syncthreads();
#pragma unroll
        for (int s2 = 0; s2 < 2; ++s2) {
            const int s = w * 2 + s2;
            const size_t ar = (size_t)(q0 + s * 16 + lr) * Dd + kk + lq * 8;
            const size_t br = (size_t)(j0 + s * 16 + lr) * Dd + kk + lq * 8;
            GLD16(Qh + ar, &Ahl[0][s][0]);
            GLD16(Ql + ar, &Ahl[1][s][0]);
            GLD16(Kh + br, &Bhl[0][s][0]);
            GLD16(Kl + br, &Bhl[1][s][0]);
        }
        __syncthreads();
        half8 ah[4], al[4], bh[4], bl[4];
#pragma unroll
        for (int i = 0; i < 4; ++i) {
            ah[i] = *(const half8*)&Ahl[0][wr + i][lane * 8];
            al[i] = *(const half8*)&Ahl[1][wr + i][lane * 8];
        }
#pragma unroll
        for (int j = 0; j < 4; ++j) {
            bh[j] = *(const half8*)&Bhl[0][wc + j][lane * 8];
            bl[j] = *(const half8*)&Bhl[1][wc + j][lane * 8];
        }
#pragma unroll
        for (int i = 0; i < 4; ++i)
#pragma unroll
            for (int j = 0; j < 4; ++j) {
                acc[i][j] = __builtin_amdgcn_mfma_f32_16x16x32_f16(ah[i], bh[j], acc[i][j], 0, 0, 0);
                acc[i][j] = __builtin_amdgcn_mfma_f32_16x16x32_f16(ah[i], bl[j], acc[i][j], 0, 0, 0);
                acc[i][j] = __builtin_amdgcn_mfma_f32_16x16x32_f16(al[i], bh[j], acc[i][j], 0, 0, 0);
            }
    }

#pragma unroll
    for (int i = 0; i < 4; ++i)
#pragma unroll
        for (int r = 0; r < 4; ++r) {
            const int q = q0 + (wr + i) * 16 + lq * 4 + r;
#pragma unroll
            for (int j = 0; j < 4; ++j) {
                const int jg = j0 + (wc + j) * 16 + lr;
                Sb[(size_t)q * Tt + jg] =
                    (jg <= q) ? floorf(acc[i][j][r] * 0.03125f) : -INFINITY;
            }
        }
}

// ---------------------------------------------------------------------------
// colstats (softmax over the QUERY axis): two-phase, tile-predicated reads
// ---------------------------------------------------------------------------
constexpr int QCH = 64;
constexpr int NCH = Tt / QCH;   // 32

__global__ __launch_bounds__(256) void colstats_part_kernel(
    const float* __restrict__ S, float* __restrict__ Pm, float* __restrict__ Pl)
{
    const int jb = blockIdx.x, qc = blockIdx.y, b = blockIdx.z;
    const int j = jb * 256 + threadIdx.x;
    const int r0 = qc * QCH;
    const size_t pidx = ((size_t)b * NCH + qc) * Tt + j;
    const int jt = j >> 7;
    const int qt = qc >> 1;
    if (jt > qt) { Pm[pidx] = -INFINITY; Pl[pidx] = 0.f; return; }
    const float* Sb = S + (size_t)b * Tt * Tt;
    float m = -INFINITY, l = 0.f;
    for (int q = r0; q < r0 + QCH; ++q) {
        const float s = Sb[(size_t)q * Tt + j];
        if (s != -INFINITY) {
            if (s > m) { l *= __expf(m - s); m = s; }
            l += __expf(s - m);
        }
    }
    Pm[pidx] = m;
    Pl[pidx] = l;
}

__global__ __launch_bounds__(256) void colstats_merge_kernel(
    const float* __restrict__ Pm, const float* __restrict__ Pl,
    float* __restrict__ Mb, float* __restrict__ Lb)
{
    const int j = blockIdx.x * 256 + threadIdx.x;
    const int b = blockIdx.y;
    float m = -INFINITY, l = 0.f;
#pragma unroll 4
    for (int c = 0; c < NCH; ++c) {
        const size_t pidx = ((size_t)b * NCH + c) * Tt + j;
        const float mi = Pm[pidx];
        if (mi == -INFINITY) continue;
        const float li = Pl[pidx];
        if (mi > m) { l = l * __expf(m - mi) + li; m = mi; }
        else        { l += li * __expf(mi - m); }
    }
    Mb[(size_t)b * Tt + j] = m;
    Lb[(size_t)b * Tt + j] = (l > 0.f) ? 1.f / l : 0.f;
}

// ---------------------------------------------------------------------------
// P = exp(S - m[k]) * invl[k] as fp16, zeros above the diagonal.
// ---------------------------------------------------------------------------
__global__ __launch_bounds__(256) void pmat_kernel(
    const float* __restrict__ S, const float* __restrict__ Mb,
    const float* __restrict__ Lb, _Float16* __restrict__ P)
{
    const size_t gid = ((size_t)blockIdx.x * 256 + threadIdx.x) * 8;
    const int b = (int)(gid >> 22);
    const int rem = (int)(gid & ((1u << 22) - 1));
    const int q = rem >> 11;
    const int k0 = rem & 2047;
    half8 out = {0, 0, 0, 0, 0, 0, 0, 0};
    if ((k0 >> 7) <= (q >> 7)) {
        const float* Sp = S + (size_t)b * Tt * Tt + (size_t)q * Tt + k0;
        const float* mp = Mb + (size_t)b * Tt + k0;
        const float* lp = Lb + (size_t)b * Tt + k0;
#pragma unroll
        for (int i = 0; i < 8; ++i)
            out[i] = f2h(__expf(Sp[i] - mp[i]) * lp[i]);
    }
    *(half8*)(P + gid) = out;
}

// ---------------------------------------------------------------------------
// Kernel 3: context = P @ V.  Single-product fp16 MFMA, causal k-truncation.
// ---------------------------------------------------------------------------
__global__ __launch_bounds__(256) void context_mfma_kernel(
    const _Float16* __restrict__ P, const _Float16* __restrict__ Vt,
    float* __restrict__ Out)
{
    __shared__ _Float16 Al[8][512];
    __shared__ _Float16 Bl[8][512];

    const int bx = blockIdx.x;
    const int by = (int)gridDim.y - 1 - blockIdx.y;  // heavy q-blocks first
    const int b  = blockIdx.z;
    const int d0 = bx * 128;
    const int q0 = by * 128;
    const _Float16* Pb = P + (size_t)b * Tt * Tt;
    const _Float16* Vb = Vt + (size_t)b * Dd * Tt;
    float* Ob = Out + (size_t)b * Tt * Dd;

    const int tid = threadIdx.x;
    const int w = tid >> 6, lane = tid & 63;
    const int lr = lane & 15, lq = lane >> 4;
    const int wr = (w >> 1) * 4, wc = (w & 1) * 4;

    f32x4 acc[4][4];
#pragma unroll
    for (int i = 0; i < 4; ++i)
#pragma unroll
        for (int j = 0; j < 4; ++j)
#pragma unroll
            for (int c = 0; c < 4; ++c) acc[i][j][c] = 0.f;

    const int kmax = q0 + 128;
    for (int k0 = 0; k0 < kmax; k0 += 32) {
        __syncthreads();
#pragma unroll
        for (int s2 = 0; s2 < 2; ++s2) {
            const int s = w * 2 + s2;
            GLD16(Pb + (size_t)(q0 + s * 16 + lr) * Tt + k0 + lq * 8, &Al[s][0]);
            GLD16(Vb + (size_t)(d0 + s * 16 + lr) * Tt + k0 + lq * 8, &Bl[s][0]);
        }
        __syncthreads();
        half8 a[4], b2[4];
#pragma unroll
        for (int i = 0; i < 4; ++i) a[i] = *(const half8*)&Al[wr + i][lane * 8];
#pragma unroll
        for (int j = 0; j < 4; ++j) b2[j] = *(const half8*)&Bl[wc + j][lane * 8];
#pragma unroll
        for (int i = 0; i < 4; ++i)
#pragma unroll
            for (int j = 0; j < 4; ++j)
                acc[i][j] = __builtin_amdgcn_mfma_f32_16x16x32_f16(a[i], b2[j], acc[i][j], 0, 0, 0);
    }

#pragma unroll
    for (int i = 0; i < 4; ++i)
#pragma unroll
        for (int r = 0; r < 4; ++r) {
            const int row = q0 + (wr + i) * 16 + lq * 4 + r;
#pragma unroll
            for (int j = 0; j < 4; ++j) {
                const int col = d0 + (wc + j) * 16 + lr;
                Ob[(size_t)row * Dd + col] = acc[i][j][r];
            }
        }
}

}  // namespace

extern "C" void kernel_launch(void* const* d_in, const int* in_sizes, int n_in,
                              void* d_out, int out_size, void* d_ws, size_t ws_size,
                              hipStream_t stream)
{
    const float* X  = (const float*)d_in[0];
    const float* Wq = (const float*)d_in[1];
    const float* Wk = (const float*)d_in[2];
    const float* Wv = (const float*)d_in[3];

    char* ws = (char*)d_ws;
    _Float16* Xhi  = (_Float16*)ws;
    _Float16* Xlo  = Xhi + (size_t)BT * Dd;
    _Float16* Whit = Xlo + (size_t)BT * Dd;
    _Float16* Wlot = Whit + (size_t)3 * Dd * Dd;
    float*    S    = (float*)ws;                       // overlay
    char* p1 = ws + (size_t)64 * 1024 * 1024;
    _Float16* Vrow = (_Float16*)p1;
    _Float16* Vt   = Vrow + (size_t)BT * Dd;
    char* p2 = p1 + (size_t)32 * 1024 * 1024;
    _Float16* Qhi = (_Float16*)p2;
    _Float16* Qlo = Qhi + (size_t)BT * Dd;
    _Float16* Khi = Qlo + (size_t)BT * Dd;
    _Float16* Klo = Khi + (size_t)BT * Dd;
    _Float16* P   = Qhi;                               // overlay after scores
    float*    Mb  = (float*)(Klo + (size_t)BT * Dd);
    float*    Lb  = Mb + (size_t)Bb * Tt;
    float*    Pm  = Lb + (size_t)Bb * Tt;
    float*    Pl  = Pm + (size_t)Bb * NCH * Tt;
    float*    Out = (float*)d_out;

    convert_x_kernel<<<BT * Dd / 1024, 256, 0, stream>>>(X, Xhi, Xlo);
    convert_w_kernel<<<dim3(16, 16, 3), 256, 0, stream>>>(Wq, Wk, Wv, Whit, Wlot);
    qkv_mfma_kernel<<<dim3(24, 64), 256, 0, stream>>>(Xhi, Xlo, Whit, Wlot,
                                                      Qhi, Qlo, Khi, Klo, Vrow);
    transpose_v_kernel<<<dim3(Dd / 64, Tt / 64, Bb), 256, 0, stream>>>(Vrow, Vt);
    scores_mfma_kernel<<<dim3(136, 1, Bb), 256, 0, stream>>>(Qhi, Qlo, Khi, Klo, S);
    colstats_part_kernel<<<dim3(Tt / 256, NCH, Bb), 256, 0, stream>>>(S, Pm, Pl);
    colstats_merge_kernel<<<dim3(Tt / 256, Bb), 256, 0, stream>>>(Pm, Pl, Mb, Lb);
    pmat_kernel<<<(int)(((size_t)Bb * Tt * Tt / 8) / 256), 256, 0, stream>>>(S, Mb, Lb, P);
    context_mfma_kernel<<<dim3(Dd / 128, Tt / 128, Bb), 256, 0, stream>>>(P, Vt, Out);
}

// Round 6
// 533.859 us; speedup vs baseline: 3.7445x; 1.0142x over previous
//
#include <hip/hip_runtime.h>
#include <math.h>

typedef _Float16 half4 __attribute__((ext_vector_type(4)));
typedef _Float16 half8 __attribute__((ext_vector_type(8)));
typedef float f32x16 __attribute__((ext_vector_type(16)));

#define GLD16(gptr, lptr)                                                     \
    __builtin_amdgcn_global_load_lds(                                         \
        (const __attribute__((address_space(1))) unsigned int*)(gptr),        \
        (__attribute__((address_space(3))) unsigned int*)(lptr), 16, 0, 0)

namespace {

constexpr int Bb = 4;
constexpr int Tt = 2048;
constexpr int Dd = 1024;
constexpr int BT = Bb * Tt;   // 8192

__device__ inline _Float16 f2h(float f) { return (_Float16)f; }

// ---------------------------------------------------------------------------
// convert X: fp32 [BT][D] -> Xhi, Xlo fp16
// ---------------------------------------------------------------------------
__global__ __launch_bounds__(256) void convert_x_kernel(
    const float* __restrict__ X, _Float16* __restrict__ Xhi, _Float16* __restrict__ Xlo)
{
    const int idx = (blockIdx.x * 256 + threadIdx.x) * 4;
    const float4 v = *(const float4*)(X + idx);
    const float a[4] = {v.x, v.y, v.z, v.w};
    half4 h, l;
#pragma unroll
    for (int i = 0; i < 4; ++i) {
        h[i] = f2h(a[i]);
        l[i] = f2h(a[i] - (float)h[i]);
    }
    *(half4*)(Xhi + idx) = h;
    *(half4*)(Xlo + idx) = l;
}

// ---------------------------------------------------------------------------
// convert+transpose W: fp32 W[k][n] -> Whit[n][k], Wlot[n][k] fp16 (3 mats)
// ---------------------------------------------------------------------------
__global__ __launch_bounds__(256) void convert_w_kernel(
    const float* __restrict__ W0, const float* __restrict__ W1,
    const float* __restrict__ W2,
    _Float16* __restrict__ Whit, _Float16* __restrict__ Wlot)
{
    const int mat = blockIdx.z;
    const float* W = (mat == 0) ? W0 : (mat == 1) ? W1 : W2;
    _Float16* Ht = Whit + (size_t)mat * Dd * Dd;
    _Float16* Lt = Wlot + (size_t)mat * Dd * Dd;
    __shared__ float tile[64][65];
    const int n0 = blockIdx.x * 64, k0 = blockIdx.y * 64;
    const int tx = threadIdx.x & 63, ty = threadIdx.x >> 6;
#pragma unroll
    for (int i = 0; i < 16; ++i)
        tile[ty + i * 4][tx] = W[(size_t)(k0 + ty + i * 4) * Dd + n0 + tx];
    __syncthreads();
#pragma unroll
    for (int i = 0; i < 16; ++i) {
        const float v = tile[tx][ty + i * 4];
        const size_t o = (size_t)(n0 + ty + i * 4) * Dd + k0 + tx;
        const _Float16 h = f2h(v);
        Ht[o] = h;
        Lt[o] = f2h(v - (float)h);
    }
}

// ---------------------------------------------------------------------------
// 32x32x16_f16 split-GEMM core: 128x128 tile, 4 waves x (2x2) 32x32 tiles.
// LDS fragment-blocked: sub-tile (r,h) = 32 rows x 16 k = 64 lanes x 16B.
// Frag layout: m = lane&31, k = (lane>>5)*8 + j  (generalizes verified 16x16).
// C/D (HW-verified): col = lane&31, row = (reg&3) + 8*(reg>>2) + 4*(lane>>5).
// ---------------------------------------------------------------------------

// Kernel 1: QKV.  Q,K: 3 products (hi.hi+hi.lo+lo.hi) -> fp16 hi/lo out.
//                 V: single hi.hi product -> fp16 row-major.
__global__ __launch_bounds__(256, 3) void qkv_mfma_kernel(
    const _Float16* __restrict__ Xhi, const _Float16* __restrict__ Xlo,
    const _Float16* __restrict__ Whit, const _Float16* __restrict__ Wlot,
    _Float16* __restrict__ Qhi, _Float16* __restrict__ Qlo,
    _Float16* __restrict__ Khi, _Float16* __restrict__ Klo,
    _Float16* __restrict__ Vrow)
{
    __shared__ _Float16 Ahl[2][8][512];
    __shared__ _Float16 Bhl[2][8][512];

    const int mat = blockIdx.x >> 3;
    const int n0 = (blockIdx.x & 7) * 128;
    const int m0 = blockIdx.y * 128;
    const _Float16* WhT = Whit + (size_t)mat * Dd * Dd;
    const _Float16* WlT = Wlot + (size_t)mat * Dd * Dd;

    const int tid = threadIdx.x;
    const int w = tid >> 6, lane = tid & 63;
    const int lm = lane & 31;          // m/n within a 32-tile
    const int lk = (lane >> 5) * 8;    // k offset within 16
    const int wi = (w >> 1) * 2;       // wave row sub-tile base (32-row units)
    const int wj = (w & 1) * 2;        // wave col sub-tile base
    const int rbase = 4 * (lane >> 5);

    f32x16 acc[2][2];
#pragma unroll
    for (int i = 0; i < 2; ++i)
#pragma unroll
        for (int j = 0; j < 2; ++j)
#pragma unroll
            for (int c = 0; c < 16; ++c) acc[i][j][c] = 0.f;

    if (mat < 2) {
        const _Float16* gsrc = (w == 0) ? Xhi : (w == 1) ? Xlo : (w == 2) ? WhT : WlT;
        const int gbase = (w < 2) ? m0 : n0;
        _Float16* ldst = (w == 0) ? &Ahl[0][0][0] : (w == 1) ? &Ahl[1][0][0]
                       : (w == 2) ? &Bhl[0][0][0] : &Bhl[1][0][0];
        for (int kk = 0; kk < 1024; kk += 32) {
            __syncthreads();
#pragma unroll
            for (int s = 0; s < 8; ++s) {
                const int r = s >> 1, h = s & 1;
                GLD16(gsrc + (size_t)(gbase + r * 32 + lm) * Dd + kk + h * 16 + lk,
                      ldst + s * 512);
            }
            __syncthreads();
#pragma unroll
            for (int h = 0; h < 2; ++h) {
                half8 ah[2], al[2], bh[2], bl[2];
#pragma unroll
                for (int i = 0; i < 2; ++i) {
                    ah[i] = *(const half8*)&Ahl[0][(wi + i) * 2 + h][lane * 8];
                    al[i] = *(const half8*)&Ahl[1][(wi + i) * 2 + h][lane * 8];
                }
#pragma unroll
                for (int j = 0; j < 2; ++j) {
                    bh[j] = *(const half8*)&Bhl[0][(wj + j) * 2 + h][lane * 8];
                    bl[j] = *(const half8*)&Bhl[1][(wj + j) * 2 + h][lane * 8];
                }
#pragma unroll
                for (int i = 0; i < 2; ++i)
#pragma unroll
                    for (int j = 0; j < 2; ++j) {
                        acc[i][j] = __builtin_amdgcn_mfma_f32_32x32x16_f16(ah[i], bh[j], acc[i][j], 0, 0, 0);
                        acc[i][j] = __builtin_amdgcn_mfma_f32_32x32x16_f16(ah[i], bl[j], acc[i][j], 0, 0, 0);
                        acc[i][j] = __builtin_amdgcn_mfma_f32_32x32x16_f16(al[i], bh[j], acc[i][j], 0, 0, 0);
                    }
            }
        }
        _Float16* Hh = mat ? Khi : Qhi;
        _Float16* Ll = mat ? Klo : Qlo;
#pragma unroll
        for (int i = 0; i < 2; ++i)
#pragma unroll
            for (int j = 0; j < 2; ++j) {
                const int col = n0 + (wj + j) * 32 + lm;
#pragma unroll
                for (int g = 0; g < 4; ++g)
#pragma unroll
                    for (int r = 0; r < 4; ++r) {
                        const int row = m0 + (wi + i) * 32 + rbase + 8 * g + r;
                        const float v = acc[i][j][g * 4 + r];
                        const _Float16 h = f2h(v);
                        Hh[(size_t)row * Dd + col] = h;
                        Ll[(size_t)row * Dd + col] = f2h(v - (float)h);
                    }
            }
    } else {
        // V: single product, stage only hi planes
        const _Float16* gsrc = (w < 2) ? Xhi : WhT;
        const int gbase = (w < 2) ? m0 : n0;
        _Float16* ldst = (w < 2) ? &Ahl[0][0][0] : &Bhl[0][0][0];
        const int s0 = (w & 1) * 4;
        for (int kk = 0; kk < 1024; kk += 32) {
            __syncthreads();
#pragma unroll
            for (int s4 = 0; s4 < 4; ++s4) {
                const int s = s0 + s4;
                const int r = s >> 1, h = s & 1;
                GLD16(gsrc + (size_t)(gbase + r * 32 + lm) * Dd + kk + h * 16 + lk,
                      ldst + s * 512);
            }
            __syncthreads();
#pragma unroll
            for (int h = 0; h < 2; ++h) {
                half8 ah[2], bh[2];
#pragma unroll
                for (int i = 0; i < 2; ++i)
                    ah[i] = *(const half8*)&Ahl[0][(wi + i) * 2 + h][lane * 8];
#pragma unroll
                for (int j = 0; j < 2; ++j)
                    bh[j] = *(const half8*)&Bhl[0][(wj + j) * 2 + h][lane * 8];
#pragma unroll
                for (int i = 0; i < 2; ++i)
#pragma unroll
                    for (int j = 0; j < 2; ++j)
                        acc[i][j] = __builtin_amdgcn_mfma_f32_32x32x16_f16(ah[i], bh[j], acc[i][j], 0, 0, 0);
            }
        }
#pragma unroll
        for (int i = 0; i < 2; ++i)
#pragma unroll
            for (int j = 0; j < 2; ++j) {
                const int col = n0 + (wj + j) * 32 + lm;
#pragma unroll
                for (int g = 0; g < 4; ++g)
#pragma unroll
                    for (int r = 0; r < 4; ++r) {
                        const int row = m0 + (wi + i) * 32 + rbase + 8 * g + r;
                        Vrow[(size_t)row * Dd + col] = f2h(acc[i][j][g * 4 + r]);
                    }
            }
    }
}

// ---------------------------------------------------------------------------
// transpose V: fp16 [b][t][d] -> Vt [b][d][t]
// ---------------------------------------------------------------------------
__global__ __launch_bounds__(256) void transpose_v_kernel(
    const _Float16* __restrict__ Vrow, _Float16* __restrict__ Vt)
{
    __shared__ _Float16 tile[64][78];
    const int d0 = blockIdx.x * 64, t0 = blockIdx.y * 64, b = blockIdx.z;
    const int tx = threadIdx.x & 63, ty = threadIdx.x >> 6;
#pragma unroll
    for (int i = 0; i < 16; ++i)
        tile[ty + i * 4][tx] = Vrow[((size_t)b * Tt + t0 + ty + i * 4) * Dd + d0 + tx];
    __syncthreads();
#pragma unroll
    for (int i = 0; i < 16; ++i)
        Vt[(size_t)b * Dd * Tt + (size_t)(d0 + ty + i * 4) * Tt + t0 + tx] = tile[tx][ty + i * 4];
}

// ---------------------------------------------------------------------------
// Kernel 2: scores, compact lower-triangle grid (136 tiles x Bb).
// ---------------------------------------------------------------------------
__global__ __launch_bounds__(256, 3) void scores_mfma_kernel(
    const _Float16* __restrict__ Qhi, const _Float16* __restrict__ Qlo,
    const _Float16* __restrict__ Khi, const _Float16* __restrict__ Klo,
    float* __restrict__ S)
{
    const int t = blockIdx.x;
    int byi = (int)((sqrtf(8.f * t + 1.f) - 1.f) * 0.5f);
    if ((byi + 1) * (byi + 2) / 2 <= t) ++byi;
    if (byi * (byi + 1) / 2 > t) --byi;
    const int bxi = t - byi * (byi + 1) / 2;
    const int b = blockIdx.z;
    const int j0 = bxi * 128, q0 = byi * 128;
    float* Sb = S + (size_t)b * Tt * Tt;

    __shared__ _Float16 Ahl[2][8][512];
    __shared__ _Float16 Bhl[2][8][512];
    const _Float16* Qh = Qhi + (size_t)b * Tt * Dd;
    const _Float16* Ql = Qlo + (size_t)b * Tt * Dd;
    const _Float16* Kh = Khi + (size_t)b * Tt * Dd;
    const _Float16* Kl = Klo + (size_t)b * Tt * Dd;

    const int tid = threadIdx.x;
    const int w = tid >> 6, lane = tid & 63;
    const int lm = lane & 31;
    const int lk = (lane >> 5) * 8;
    const int wi = (w >> 1) * 2;
    const int wj = (w & 1) * 2;
    const int rbase = 4 * (lane >> 5);

    f32x16 acc[2][2];
#pragma unroll
    for (int i = 0; i < 2; ++i)
#pragma unroll
        for (int j = 0; j < 2; ++j)
#pragma unroll
            for (int c = 0; c < 16; ++c) acc[i][j][c] = 0.f;

    const _Float16* gsrc = (w == 0) ? Qh : (w == 1) ? Ql : (w == 2) ? Kh : Kl;
    const int gbase = (w < 2) ? q0 : j0;
    _Float16* ldst = (w == 0) ? &Ahl[0][0][0] : (w == 1) ? &Ahl[1][0][0]
                   : (w == 2) ? &Bhl[0][0][0] : &Bhl[1][0][0];
    for (int kk = 0; kk < 1024; kk += 32) {
        __syncthreads();
#pragma unroll
        for (int s = 0; s < 8; ++s) {
            const int r = s >> 1, h = s & 1;
            GLD16(gsrc + (size_t)(gbase + r * 32 + lm) * Dd + kk + h * 16 + lk,
                  ldst + s * 512);
        }
        __syncthreads();
#pragma unroll
        for (int h = 0; h < 2; ++h) {
            half8 ah[2], al[2], bh[2], bl[2];
#pragma unroll
            for (int i = 0; i < 2; ++i) {
                ah[i] = *(const half8*)&Ahl[0][(wi + i) * 2 + h][lane * 8];
                al[i] = *(const half8*)&Ahl[1][(wi + i) * 2 + h][lane * 8];
            }
#pragma unroll
            for (int j = 0; j < 2; ++j) {
                bh[j] = *(const half8*)&Bhl[0][(wj + j) * 2 + h][lane * 8];
                bl[j] = *(const half8*)&Bhl[1][(wj + j) * 2 + h][lane * 8];
            }
#pragma unroll
            for (int i = 0; i < 2; ++i)
#pragma unroll
                for (int j = 0; j < 2; ++j) {
                    acc[i][j] = __builtin_amdgcn_mfma_f32_32x32x16_f16(ah[i], bh[j], acc[i][j], 0, 0, 0);
                    acc[i][j] = __builtin_amdgcn_mfma_f32_32x32x16_f16(ah[i], bl[j], acc[i][j], 0, 0, 0);
                    acc[i][j] = __builtin_amdgcn_mfma_f32_32x32x16_f16(al[i], bh[j], acc[i][j], 0, 0, 0);
                }
        }
    }

#pragma unroll
    for (int i = 0; i < 2; ++i)
#pragma unroll
        for (int j = 0; j < 2; ++j) {
            const int jg = j0 + (wj + j) * 32 + lm;
#pragma unroll
            for (int g = 0; g < 4; ++g)
#pragma unroll
                for (int r = 0; r < 4; ++r) {
                    const int q = q0 + (wi + i) * 32 + rbase + 8 * g + r;
                    Sb[(size_t)q * Tt + jg] =
                        (jg <= q) ? floorf(acc[i][j][g * 4 + r] * 0.03125f) : -INFINITY;
                }
        }
}

// ---------------------------------------------------------------------------
// colstats (softmax over the QUERY axis): two-phase, tile-predicated reads
// ---------------------------------------------------------------------------
constexpr int QCH = 64;
constexpr int NCH = Tt / QCH;   // 32

__global__ __launch_bounds__(256) void colstats_part_kernel(
    const float* __restrict__ S, float* __restrict__ Pm, float* __restrict__ Pl)
{
    const int jb = blockIdx.x, qc = blockIdx.y, b = blockIdx.z;
    const int j = jb * 256 + threadIdx.x;
    const int r0 = qc * QCH;
    const size_t pidx = ((size_t)b * NCH + qc) * Tt + j;
    const int jt = j >> 7;
    const int qt = qc >> 1;
    if (jt > qt) { Pm[pidx] = -INFINITY; Pl[pidx] = 0.f; return; }
    const float* Sb = S + (size_t)b * Tt * Tt;
    float m = -INFINITY, l = 0.f;
    for (int q = r0; q < r0 + QCH; ++q) {
        const float s = Sb[(size_t)q * Tt + j];
        if (s != -INFINITY) {
            if (s > m) { l *= __expf(m - s); m = s; }
            l += __expf(s - m);
        }
    }
    Pm[pidx] = m;
    Pl[pidx] = l;
}

__global__ __launch_bounds__(256) void colstats_merge_kernel(
    const float* __restrict__ Pm, const float* __restrict__ Pl,
    float* __restrict__ Mb, float* __restrict__ Lb)
{
    const int j = blockIdx.x * 256 + threadIdx.x;
    const int b = blockIdx.y;
    float m = -INFINITY, l = 0.f;
#pragma unroll 4
    for (int c = 0; c < NCH; ++c) {
        const size_t pidx = ((size_t)b * NCH + c) * Tt + j;
        const float mi = Pm[pidx];
        if (mi == -INFINITY) continue;
        const float li = Pl[pidx];
        if (mi > m) { l = l * __expf(m - mi) + li; m = mi; }
        else        { l += li * __expf(mi - m); }
    }
    Mb[(size_t)b * Tt + j] = m;
    Lb[(size_t)b * Tt + j] = (l > 0.f) ? 1.f / l : 0.f;
}

// ---------------------------------------------------------------------------
// P = exp(S - m[k]) * invl[k] as fp16, zeros above the diagonal.
// ---------------------------------------------------------------------------
__global__ __launch_bounds__(256) void pmat_kernel(
    const float* __restrict__ S, const float* __restrict__ Mb,
    const float* __restrict__ Lb, _Float16* __restrict__ P)
{
    const size_t gid = ((size_t)blockIdx.x * 256 + threadIdx.x) * 8;
    const int b = (int)(gid >> 22);
    const int rem = (int)(gid & ((1u << 22) - 1));
    const int q = rem >> 11;
    const int k0 = rem & 2047;
    half8 out = {0, 0, 0, 0, 0, 0, 0, 0};
    if ((k0 >> 7) <= (q >> 7)) {
        const float* Sp = S + (size_t)b * Tt * Tt + (size_t)q * Tt + k0;
        const float* mp = Mb + (size_t)b * Tt + k0;
        const float* lp = Lb + (size_t)b * Tt + k0;
#pragma unroll
        for (int i = 0; i < 8; ++i)
            out[i] = f2h(__expf(Sp[i] - mp[i]) * lp[i]);
    }
    *(half8*)(P + gid) = out;
}

// ---------------------------------------------------------------------------
// Kernel 3: context = P @ V.  Single-product 32x32 MFMA, causal k-truncation.
// ---------------------------------------------------------------------------
__global__ __launch_bounds__(256, 3) void context_mfma_kernel(
    const _Float16* __restrict__ P, const _Float16* __restrict__ Vt,
    float* __restrict__ Out)
{
    __shared__ _Float16 Al[8][512];
    __shared__ _Float16 Bl[8][512];

    const int bx = blockIdx.x;
    const int by = (int)gridDim.y - 1 - blockIdx.y;  // heavy q-blocks first
    const int b  = blockIdx.z;
    const int d0 = bx * 128;
    const int q0 = by * 128;
    const _Float16* Pb = P + (size_t)b * Tt * Tt;
    const _Float16* Vb = Vt + (size_t)b * Dd * Tt;
    float* Ob = Out + (size_t)b * Tt * Dd;

    const int tid = threadIdx.x;
    const int w = tid >> 6, lane = tid & 63;
    const int lm = lane & 31;
    const int lk = (lane >> 5) * 8;
    const int wi = (w >> 1) * 2;
    const int wj = (w & 1) * 2;
    const int rbase = 4 * (lane >> 5);

    f32x16 acc[2][2];
#pragma unroll
    for (int i = 0; i < 2; ++i)
#pragma unroll
        for (int j = 0; j < 2; ++j)
#pragma unroll
            for (int c = 0; c < 16; ++c) acc[i][j][c] = 0.f;

    const _Float16* gsrc = (w < 2) ? Pb : Vb;
    const size_t gstride = Tt;
    const int gbase = (w < 2) ? q0 : d0;
    _Float16* ldst = (w < 2) ? &Al[0][0] : &Bl[0][0];
    const int s0 = (w & 1) * 4;

    const int kmax = q0 + 128;   // P zero for k > q
    for (int k0 = 0; k0 < kmax; k0 += 32) {
        __syncthreads();
#pragma unroll
        for (int s4 = 0; s4 < 4; ++s4) {
            const int s = s0 + s4;
            const int r = s >> 1, h = s & 1;
            GLD16(gsrc + (size_t)(gbase + r * 32 + lm) * gstride + k0 + h * 16 + lk,
                  ldst + s * 512);
        }
        __syncthreads();
#pragma unroll
        for (int h = 0; h < 2; ++h) {
            half8 a[2], b2[2];
#pragma unroll
            for (int i = 0; i < 2; ++i)
                a[i] = *(const half8*)&Al[(wi + i) * 2 + h][lane * 8];
#pragma unroll
            for (int j = 0; j < 2; ++j)
                b2[j] = *(const half8*)&Bl[(wj + j) * 2 + h][lane * 8];
#pragma unroll
            for (int i = 0; i < 2; ++i)
#pragma unroll
                for (int j = 0; j < 2; ++j)
                    acc[i][j] = __builtin_amdgcn_mfma_f32_32x32x16_f16(a[i], b2[j], acc[i][j], 0, 0, 0);
        }
    }

#pragma unroll
    for (int i = 0; i < 2; ++i)
#pragma unroll
        for (int j = 0; j < 2; ++j) {
            const int col = d0 + (wj + j) * 32 + lm;
#pragma unroll
            for (int g = 0; g < 4; ++g)
#pragma unroll
                for (int r = 0; r < 4; ++r) {
                    const int row = q0 + (wi + i) * 32 + rbase + 8 * g + r;
                    Ob[(size_t)row * Dd + col] = acc[i][j][g * 4 + r];
                }
        }
}

}  // namespace

extern "C" void kernel_launch(void* const* d_in, const int* in_sizes, int n_in,
                              void* d_out, int out_size, void* d_ws, size_t ws_size,
                              hipStream_t stream)
{
    const float* X  = (const float*)d_in[0];
    const float* Wq = (const float*)d_in[1];
    const float* Wk = (const float*)d_in[2];
    const float* Wv = (const float*)d_in[3];

    char* ws = (char*)d_ws;
    _Float16* Xhi  = (_Float16*)ws;
    _Float16* Xlo  = Xhi + (size_t)BT * Dd;
    _Float16* Whit = Xlo + (size_t)BT * Dd;
    _Float16* Wlot = Whit + (size_t)3 * Dd * Dd;
    float*    S    = (float*)ws;                       // overlay (X/W dead)
    char* p1 = ws + (size_t)64 * 1024 * 1024;
    _Float16* Vrow = (_Float16*)p1;
    _Float16* Vt   = Vrow + (size_t)BT * Dd;
    char* p2 = p1 + (size_t)32 * 1024 * 1024;
    _Float16* Qhi = (_Float16*)p2;
    _Float16* Qlo = Qhi + (size_t)BT * Dd;
    _Float16* Khi = Qlo + (size_t)BT * Dd;
    _Float16* Klo = Khi + (size_t)BT * Dd;
    _Float16* P   = Qhi;                               // overlay after scores
    float*    Mb  = (float*)(Klo + (size_t)BT * Dd);
    float*    Lb  = Mb + (size_t)Bb * Tt;
    float*    Pm  = Lb + (size_t)Bb * Tt;
    float*    Pl  = Pm + (size_t)Bb * NCH * Tt;
    float*    Out = (float*)d_out;

    convert_x_kernel<<<BT * Dd / 1024, 256, 0, stream>>>(X, Xhi, Xlo);
    convert_w_kernel<<<dim3(16, 16, 3), 256, 0, stream>>>(Wq, Wk, Wv, Whit, Wlot);
    qkv_mfma_kernel<<<dim3(24, 64), 256, 0, stream>>>(Xhi, Xlo, Whit, Wlot,
                                                      Qhi, Qlo, Khi, Klo, Vrow);
    transpose_v_kernel<<<dim3(Dd / 64, Tt / 64, Bb), 256, 0, stream>>>(Vrow, Vt);
    scores_mfma_kernel<<<dim3(136, 1, Bb), 256, 0, stream>>>(Qhi, Qlo, Khi, Klo, S);
    colstats_part_kernel<<<dim3(Tt / 256, NCH, Bb), 256, 0, stream>>>(S, Pm, Pl);
    colstats_merge_kernel<<<dim3(Tt / 256, Bb), 256, 0, stream>>>(Pm, Pl, Mb, Lb);
    pmat_kernel<<<(int)(((size_t)Bb * Tt * Tt / 8) / 256), 256, 0, stream>>>(S, Mb, Lb, P);
    context_mfma_kernel<<<dim3(Dd / 128, Tt / 128, Bb), 256, 0, stream>>>(P, Vt, Out);
}

// Round 7
// 502.222 us; speedup vs baseline: 3.9804x; 1.0630x over previous
//
#include <hip/hip_runtime.h>
#include <math.h>

typedef _Float16 half4 __attribute__((ext_vector_type(4)));
typedef _Float16 half8 __attribute__((ext_vector_type(8)));
typedef float f32x4 __attribute__((ext_vector_type(4)));

#define GLD16(gptr, lptr)                                                     \
    __builtin_amdgcn_global_load_lds(                                         \
        (const __attribute__((address_space(1))) unsigned int*)(gptr),        \
        (__attribute__((address_space(3))) unsigned int*)(lptr), 16, 0, 0)

namespace {

constexpr int Bb = 4;
constexpr int Tt = 2048;
constexpr int Dd = 1024;
constexpr int BT = Bb * Tt;   // 8192

__device__ inline _Float16 f2h(float f) { return (_Float16)f; }

// ---------------------------------------------------------------------------
// convert X: fp32 [BT][D] -> Xhi, Xlo fp16
// ---------------------------------------------------------------------------
__global__ __launch_bounds__(256) void convert_x_kernel(
    const float* __restrict__ X, _Float16* __restrict__ Xhi, _Float16* __restrict__ Xlo)
{
    const int idx = (blockIdx.x * 256 + threadIdx.x) * 4;
    const float4 v = *(const float4*)(X + idx);
    const float a[4] = {v.x, v.y, v.z, v.w};
    half4 h, l;
#pragma unroll
    for (int i = 0; i < 4; ++i) {
        h[i] = f2h(a[i]);
        l[i] = f2h(a[i] - (float)h[i]);
    }
    *(half4*)(Xhi + idx) = h;
    *(half4*)(Xlo + idx) = l;
}

// ---------------------------------------------------------------------------
// convert Wq,Wk (NO transpose): fp32 [r][a] -> hi/lo fp16 [r][a]
// ---------------------------------------------------------------------------
__global__ __launch_bounds__(256) void convert_wqk_kernel(
    const float* __restrict__ Wq, const float* __restrict__ Wk,
    _Float16* __restrict__ Wqh, _Float16* __restrict__ Wql,
    _Float16* __restrict__ Wkh, _Float16* __restrict__ Wkl)
{
    const int mat = blockIdx.y;
    const float* W = mat ? Wk : Wq;
    _Float16* Hh = mat ? Wkh : Wqh;
    _Float16* Ll = mat ? Wkl : Wql;
    const int idx = (blockIdx.x * 256 + threadIdx.x) * 4;
    const float4 v = *(const float4*)(W + idx);
    const float a[4] = {v.x, v.y, v.z, v.w};
    half4 h, l;
#pragma unroll
    for (int i = 0; i < 4; ++i) {
        h[i] = f2h(a[i]);
        l[i] = f2h(a[i] - (float)h[i]);
    }
    *(half4*)(Hh + idx) = h;
    *(half4*)(Ll + idx) = l;
}

// ---------------------------------------------------------------------------
// convert+transpose Wv: fp32 Wv[r][n] -> WvT[n][r] hi fp16 (single product)
// ---------------------------------------------------------------------------
__global__ __launch_bounds__(256) void convert_wv_kernel(
    const float* __restrict__ Wv, _Float16* __restrict__ WvTh)
{
    __shared__ float tile[64][65];
    const int n0 = blockIdx.x * 64, k0 = blockIdx.y * 64;
    const int tx = threadIdx.x & 63, ty = threadIdx.x >> 6;
#pragma unroll
    for (int i = 0; i < 16; ++i)
        tile[ty + i * 4][tx] = Wv[(size_t)(k0 + ty + i * 4) * Dd + n0 + tx];
    __syncthreads();
#pragma unroll
    for (int i = 0; i < 16; ++i) {
        const float v = tile[tx][ty + i * 4];
        WvTh[(size_t)(n0 + ty + i * 4) * Dd + k0 + tx] = f2h(v);
    }
}

// ---------------------------------------------------------------------------
// GT[s][r] = sum_a Wk[s][a] * Wq[r][a]   (so that T = X*G has B-rows = GT[s])
// 64x64 tiles, 256 blocks, 3 split-products, 16x16x32 MFMA.
// ---------------------------------------------------------------------------
__global__ __launch_bounds__(256) void gt_kernel(
    const _Float16* __restrict__ Wkh, const _Float16* __restrict__ Wkl,
    const _Float16* __restrict__ Wqh, const _Float16* __restrict__ Wql,
    _Float16* __restrict__ GTh, _Float16* __restrict__ GTl)
{
    __shared__ _Float16 Ahl[2][4][512];
    __shared__ _Float16 Bhl[2][4][512];

    const int n0 = blockIdx.x * 64;   // r (col)
    const int m0 = blockIdx.y * 64;   // s (row)
    const int tid = threadIdx.x;
    const int w = tid >> 6, lane = tid & 63;
    const int lr = lane & 15, lq = lane >> 4;
    const int wi = (w >> 1) * 2, wj = (w & 1) * 2;

    f32x4 acc[2][2];
#pragma unroll
    for (int i = 0; i < 2; ++i)
#pragma unroll
        for (int j = 0; j < 2; ++j)
#pragma unroll
            for (int c = 0; c < 4; ++c) acc[i][j][c] = 0.f;

    for (int kk = 0; kk < 1024; kk += 32) {
        __syncthreads();
        {
            const int s = w;   // each wave stages sub-tile s of all 4 planes
            const size_t ar = (size_t)(m0 + s * 16 + lr) * Dd + kk + lq * 8;
            const size_t br = (size_t)(n0 + s * 16 + lr) * Dd + kk + lq * 8;
            GLD16(Wkh + ar, &Ahl[0][s][0]);
            GLD16(Wkl + ar, &Ahl[1][s][0]);
            GLD16(Wqh + br, &Bhl[0][s][0]);
            GLD16(Wql + br, &Bhl[1][s][0]);
        }
        __syncthreads();
        half8 ah[2], al[2], bh[2], bl[2];
#pragma unroll
        for (int i = 0; i < 2; ++i) {
            ah[i] = *(const half8*)&Ahl[0][wi + i][lane * 8];
            al[i] = *(const half8*)&Ahl[1][wi + i][lane * 8];
        }
#pragma unroll
        for (int j = 0; j < 2; ++j) {
            bh[j] = *(const half8*)&Bhl[0][wj + j][lane * 8];
            bl[j] = *(const half8*)&Bhl[1][wj + j][lane * 8];
        }
#pragma unroll
        for (int i = 0; i < 2; ++i)
#pragma unroll
            for (int j = 0; j < 2; ++j) {
                acc[i][j] = __builtin_amdgcn_mfma_f32_16x16x32_f16(ah[i], bh[j], acc[i][j], 0, 0, 0);
                acc[i][j] = __builtin_amdgcn_mfma_f32_16x16x32_f16(ah[i], bl[j], acc[i][j], 0, 0, 0);
                acc[i][j] = __builtin_amdgcn_mfma_f32_16x16x32_f16(al[i], bh[j], acc[i][j], 0, 0, 0);
            }
    }

#pragma unroll
    for (int i = 0; i < 2; ++i)
#pragma unroll
        for (int r = 0; r < 4; ++r) {
            const int row = m0 + (wi + i) * 16 + lq * 4 + r;
#pragma unroll
            for (int j = 0; j < 2; ++j) {
                const int col = n0 + (wj + j) * 16 + lr;
                const float v = acc[i][j][r];
                const _Float16 h = f2h(v);
                GTh[(size_t)row * Dd + col] = h;
                GTl[(size_t)row * Dd + col] = f2h(v - (float)h);
            }
        }
}

// ---------------------------------------------------------------------------
// tv kernel: bx<8 -> T = X*G (3 products, B-rows = GT), out T hi/lo.
//            bx>=8 -> V = X*Wv (1 product, B-rows = WvT), out fp16.
// Round-5 proven structure: 128x128 tile, interleaved all-wave staging.
// ---------------------------------------------------------------------------
__global__ __launch_bounds__(256) void tv_kernel(
    const _Float16* __restrict__ Xhi, const _Float16* __restrict__ Xlo,
    const _Float16* __restrict__ GTh, const _Float16* __restrict__ GTl,
    const _Float16* __restrict__ WvTh,
    _Float16* __restrict__ Thi, _Float16* __restrict__ Tlo,
    _Float16* __restrict__ Vrow)
{
    __shared__ _Float16 Ahl[2][8][512];
    __shared__ _Float16 Bhl[2][8][512];

    const bool isT = blockIdx.x < 8;
    const int n0 = (blockIdx.x & 7) * 128;
    const int m0 = blockIdx.y * 128;

    const int tid = threadIdx.x;
    const int w = tid >> 6, lane = tid & 63;
    const int lr = lane & 15, lq = lane >> 4;
    const int wr = (w >> 1) * 4, wc = (w & 1) * 4;

    f32x4 acc[4][4];
#pragma unroll
    for (int i = 0; i < 4; ++i)
#pragma unroll
        for (int j = 0; j < 4; ++j)
#pragma unroll
            for (int c = 0; c < 4; ++c) acc[i][j][c] = 0.f;

    if (isT) {
        for (int kk = 0; kk < 1024; kk += 32) {
            __syncthreads();
#pragma unroll
            for (int s2 = 0; s2 < 2; ++s2) {
                const int s = w * 2 + s2;
                const size_t ar = (size_t)(m0 + s * 16 + lr) * Dd + kk + lq * 8;
                const size_t br = (size_t)(n0 + s * 16 + lr) * Dd + kk + lq * 8;
                GLD16(Xhi + ar, &Ahl[0][s][0]);
                GLD16(Xlo + ar, &Ahl[1][s][0]);
                GLD16(GTh + br, &Bhl[0][s][0]);
                GLD16(GTl + br, &Bhl[1][s][0]);
            }
            __syncthreads();
            half8 ah[4], al[4], bh[4], bl[4];
#pragma unroll
            for (int i = 0; i < 4; ++i) {
                ah[i] = *(const half8*)&Ahl[0][wr + i][lane * 8];
                al[i] = *(const half8*)&Ahl[1][wr + i][lane * 8];
            }
#pragma unroll
            for (int j = 0; j < 4; ++j) {
                bh[j] = *(const half8*)&Bhl[0][wc + j][lane * 8];
                bl[j] = *(const half8*)&Bhl[1][wc + j][lane * 8];
            }
#pragma unroll
            for (int i = 0; i < 4; ++i)
#pragma unroll
                for (int j = 0; j < 4; ++j) {
                    acc[i][j] = __builtin_amdgcn_mfma_f32_16x16x32_f16(ah[i], bh[j], acc[i][j], 0, 0, 0);
                    acc[i][j] = __builtin_amdgcn_mfma_f32_16x16x32_f16(ah[i], bl[j], acc[i][j], 0, 0, 0);
                    acc[i][j] = __builtin_amdgcn_mfma_f32_16x16x32_f16(al[i], bh[j], acc[i][j], 0, 0, 0);
                }
        }
#pragma unroll
        for (int i = 0; i < 4; ++i)
#pragma unroll
            for (int r = 0; r < 4; ++r) {
                const int row = m0 + (wr + i) * 16 + lq * 4 + r;
#pragma unroll
                for (int j = 0; j < 4; ++j) {
                    const int col = n0 + (wc + j) * 16 + lr;
                    const float v = acc[i][j][r];
                    const _Float16 h = f2h(v);
                    Thi[(size_t)row * Dd + col] = h;
                    Tlo[(size_t)row * Dd + col] = f2h(v - (float)h);
                }
            }
    } else {
        for (int kk = 0; kk < 1024; kk += 32) {
            __syncthreads();
#pragma unroll
            for (int s2 = 0; s2 < 2; ++s2) {
                const int s = w * 2 + s2;
                const size_t ar = (size_t)(m0 + s * 16 + lr) * Dd + kk + lq * 8;
                const size_t br = (size_t)(n0 + s * 16 + lr) * Dd + kk + lq * 8;
                GLD16(Xhi + ar, &Ahl[0][s][0]);
                GLD16(WvTh + br, &Bhl[0][s][0]);
            }
            __syncthreads();
            half8 ah[4], bh[4];
#pragma unroll
            for (int i = 0; i < 4; ++i) ah[i] = *(const half8*)&Ahl[0][wr + i][lane * 8];
#pragma unroll
            for (int j = 0; j < 4; ++j) bh[j] = *(const half8*)&Bhl[0][wc + j][lane * 8];
#pragma unroll
            for (int i = 0; i < 4; ++i)
#pragma unroll
                for (int j = 0; j < 4; ++j)
                    acc[i][j] = __builtin_amdgcn_mfma_f32_16x16x32_f16(ah[i], bh[j], acc[i][j], 0, 0, 0);
        }
#pragma unroll
        for (int i = 0; i < 4; ++i)
#pragma unroll
            for (int r = 0; r < 4; ++r) {
                const int row = m0 + (wr + i) * 16 + lq * 4 + r;
#pragma unroll
                for (int j = 0; j < 4; ++j) {
                    const int col = n0 + (wc + j) * 16 + lr;
                    Vrow[(size_t)row * Dd + col] = f2h(acc[i][j][r]);
                }
            }
    }
}

// ---------------------------------------------------------------------------
// transpose V: fp16 [b][t][d] -> Vt [b][d][t]
// ---------------------------------------------------------------------------
__global__ __launch_bounds__(256) void transpose_v_kernel(
    const _Float16* __restrict__ Vrow, _Float16* __restrict__ Vt)
{
    __shared__ _Float16 tile[64][78];
    const int d0 = blockIdx.x * 64, t0 = blockIdx.y * 64, b = blockIdx.z;
    const int tx = threadIdx.x & 63, ty = threadIdx.x >> 6;
#pragma unroll
    for (int i = 0; i < 16; ++i)
        tile[ty + i * 4][tx] = Vrow[((size_t)b * Tt + t0 + ty + i * 4) * Dd + d0 + tx];
    __syncthreads();
#pragma unroll
    for (int i = 0; i < 16; ++i)
        Vt[(size_t)b * Dd * Tt + (size_t)(d0 + ty + i * 4) * Tt + t0 + tx] = tile[tx][ty + i * 4];
}

// ---------------------------------------------------------------------------
// scores: S[q,j] = floor( (sum_s T[q,s]*X[j,s]) / 32 ), lower-triangle tiles.
// A = T hi/lo, B = X hi/lo.  Round-5 proven structure.
// ---------------------------------------------------------------------------
__global__ __launch_bounds__(256) void scores_mfma_kernel(
    const _Float16* __restrict__ Thi, const _Float16* __restrict__ Tlo,
    const _Float16* __restrict__ Xhi, const _Float16* __restrict__ Xlo,
    float* __restrict__ S)
{
    const int t = blockIdx.x;
    int byi = (int)((sqrtf(8.f * t + 1.f) - 1.f) * 0.5f);
    if ((byi + 1) * (byi + 2) / 2 <= t) ++byi;
    if (byi * (byi + 1) / 2 > t) --byi;
    const int bxi = t - byi * (byi + 1) / 2;
    const int b = blockIdx.z;
    const int j0 = bxi * 128, q0 = byi * 128;
    float* Sb = S + (size_t)b * Tt * Tt;

    __shared__ _Float16 Ahl[2][8][512];
    __shared__ _Float16 Bhl[2][8][512];
    const _Float16* Th = Thi + (size_t)b * Tt * Dd;
    const _Float16* Tl = Tlo + (size_t)b * Tt * Dd;
    const _Float16* Xh = Xhi + (size_t)b * Tt * Dd;
    const _Float16* Xl = Xlo + (size_t)b * Tt * Dd;

    const int tid = threadIdx.x;
    const int w = tid >> 6, lane = tid & 63;
    const int lr = lane & 15, lq = lane >> 4;
    const int wr = (w >> 1) * 4, wc = (w & 1) * 4;

    f32x4 acc[4][4];
#pragma unroll
    for (int i = 0; i < 4; ++i)
#pragma unroll
        for (int j = 0; j < 4; ++j)
#pragma unroll
            for (int c = 0; c < 4; ++c) acc[i][j][c] = 0.f;

    for (int kk = 0; kk < 1024; kk += 32) {
        __syncthreads();
#pragma unroll
        for (int s2 = 0; s2 < 2; ++s2) {
            const int s = w * 2 + s2;
            const size_t ar = (size_t)(q0 + s * 16 + lr) * Dd + kk + lq * 8;
            const size_t br = (size_t)(j0 + s * 16 + lr) * Dd + kk + lq * 8;
            GLD16(Th + ar, &Ahl[0][s][0]);
            GLD16(Tl + ar, &Ahl[1][s][0]);
            GLD16(Xh + br, &Bhl[0][s][0]);
            GLD16(Xl + br, &Bhl[1][s][0]);
        }
        __syncthreads();
        half8 ah[4], al[4], bh[4], bl[4];
#pragma unroll
        for (int i = 0; i < 4; ++i) {
            ah[i] = *(const half8*)&Ahl[0][wr + i][lane * 8];
            al[i] = *(const half8*)&Ahl[1][wr + i][lane * 8];
        }
#pragma unroll
        for (int j = 0; j < 4; ++j) {
            bh[j] = *(const half8*)&Bhl[0][wc + j][lane * 8];
            bl[j] = *(const half8*)&Bhl[1][wc + j][lane * 8];
        }
#pragma unroll
        for (int i = 0; i < 4; ++i)
#pragma unroll
            for (int j = 0; j < 4; ++j) {
                acc[i][j] = __builtin_amdgcn_mfma_f32_16x16x32_f16(ah[i], bh[j], acc[i][j], 0, 0, 0);
                acc[i][j] = __builtin_amdgcn_mfma_f32_16x16x32_f16(ah[i], bl[j], acc[i][j], 0, 0, 0);
                acc[i][j] = __builtin_amdgcn_mfma_f32_16x16x32_f16(al[i], bh[j], acc[i][j], 0, 0, 0);
            }
    }

#pragma unroll
    for (int i = 0; i < 4; ++i)
#pragma unroll
        for (int r = 0; r < 4; ++r) {
            const int q = q0 + (wr + i) * 16 + lq * 4 + r;
#pragma unroll
            for (int j = 0; j < 4; ++j) {
                const int jg = j0 + (wc + j) * 16 + lr;
                Sb[(size_t)q * Tt + jg] =
                    (jg <= q) ? floorf(acc[i][j][r] * 0.03125f) : -INFINITY;
            }
        }
}

// ---------------------------------------------------------------------------
// colstats (softmax over the QUERY axis): two-phase, tile-predicated reads
// ---------------------------------------------------------------------------
constexpr int QCH = 64;
constexpr int NCH = Tt / QCH;   // 32

__global__ __launch_bounds__(256) void colstats_part_kernel(
    const float* __restrict__ S, float* __restrict__ Pm, float* __restrict__ Pl)
{
    const int jb = blockIdx.x, qc = blockIdx.y, b = blockIdx.z;
    const int j = jb * 256 + threadIdx.x;
    const int r0 = qc * QCH;
    const size_t pidx = ((size_t)b * NCH + qc) * Tt + j;
    const int jt = j >> 7;
    const int qt = qc >> 1;
    if (jt > qt) { Pm[pidx] = -INFINITY; Pl[pidx] = 0.f; return; }
    const float* Sb = S + (size_t)b * Tt * Tt;
    float m = -INFINITY, l = 0.f;
    for (int q = r0; q < r0 + QCH; ++q) {
        const float s = Sb[(size_t)q * Tt + j];
        if (s != -INFINITY) {
            if (s > m) { l *= __expf(m - s); m = s; }
            l += __expf(s - m);
        }
    }
    Pm[pidx] = m;
    Pl[pidx] = l;
}

__global__ __launch_bounds__(256) void colstats_merge_kernel(
    const float* __restrict__ Pm, const float* __restrict__ Pl,
    float* __restrict__ Mb, float* __restrict__ Lb)
{
    const int j = blockIdx.x * 256 + threadIdx.x;
    const int b = blockIdx.y;
    float m = -INFINITY, l = 0.f;
#pragma unroll 4
    for (int c = 0; c < NCH; ++c) {
        const size_t pidx = ((size_t)b * NCH + c) * Tt + j;
        const float mi = Pm[pidx];
        if (mi == -INFINITY) continue;
        const float li = Pl[pidx];
        if (mi > m) { l = l * __expf(m - mi) + li; m = mi; }
        else        { l += li * __expf(mi - m); }
    }
    Mb[(size_t)b * Tt + j] = m;
    Lb[(size_t)b * Tt + j] = (l > 0.f) ? 1.f / l : 0.f;
}

// ---------------------------------------------------------------------------
// P = exp(S - m[k]) * invl[k] as fp16, zeros above the diagonal.
// ---------------------------------------------------------------------------
__global__ __launch_bounds__(256) void pmat_kernel(
    const float* __restrict__ S, const float* __restrict__ Mb,
    const float* __restrict__ Lb, _Float16* __restrict__ P)
{
    const size_t gid = ((size_t)blockIdx.x * 256 + threadIdx.x) * 8;
    const int b = (int)(gid >> 22);
    const int rem = (int)(gid & ((1u << 22) - 1));
    const int q = rem >> 11;
    const int k0 = rem & 2047;
    half8 out = {0, 0, 0, 0, 0, 0, 0, 0};
    if ((k0 >> 7) <= (q >> 7)) {
        const float* Sp = S + (size_t)b * Tt * Tt + (size_t)q * Tt + k0;
        const float* mp = Mb + (size_t)b * Tt + k0;
        const float* lp = Lb + (size_t)b * Tt + k0;
#pragma unroll
        for (int i = 0; i < 8; ++i)
            out[i] = f2h(__expf(Sp[i] - mp[i]) * lp[i]);
    }
    *(half8*)(P + gid) = out;
}

// ---------------------------------------------------------------------------
// context = P @ V.  Single-product fp16 MFMA, causal k-truncation.
// ---------------------------------------------------------------------------
__global__ __launch_bounds__(256) void context_mfma_kernel(
    const _Float16* __restrict__ P, const _Float16* __restrict__ Vt,
    float* __restrict__ Out)
{
    __shared__ _Float16 Al[8][512];
    __shared__ _Float16 Bl[8][512];

    const int bx = blockIdx.x;
    const int by = (int)gridDim.y - 1 - blockIdx.y;  // heavy q-blocks first
    const int b  = blockIdx.z;
    const int d0 = bx * 128;
    const int q0 = by * 128;
    const _Float16* Pb = P + (size_t)b * Tt * Tt;
    const _Float16* Vb = Vt + (size_t)b * Dd * Tt;
    float* Ob = Out + (size_t)b * Tt * Dd;

    const int tid = threadIdx.x;
    const int w = tid >> 6, lane = tid & 63;
    const int lr = lane & 15, lq = lane >> 4;
    const int wr = (w >> 1) * 4, wc = (w & 1) * 4;

    f32x4 acc[4][4];
#pragma unroll
    for (int i = 0; i < 4; ++i)
#pragma unroll
        for (int j = 0; j < 4; ++j)
#pragma unroll
            for (int c = 0; c < 4; ++c) acc[i][j][c] = 0.f;

    const int kmax = q0 + 128;
    for (int k0 = 0; k0 < kmax; k0 += 32) {
        __syncthreads();
#pragma unroll
        for (int s2 = 0; s2 < 2; ++s2) {
            const int s = w * 2 + s2;
            GLD16(Pb + (size_t)(q0 + s * 16 + lr) * Tt + k0 + lq * 8, &Al[s][0]);
            GLD16(Vb + (size_t)(d0 + s * 16 + lr) * Tt + k0 + lq * 8, &Bl[s][0]);
        }
        __syncthreads();
        half8 a[4], b2[4];
#pragma unroll
        for (int i = 0; i < 4; ++i) a[i] = *(const half8*)&Al[wr + i][lane * 8];
#pragma unroll
        for (int j = 0; j < 4; ++j) b2[j] = *(const half8*)&Bl[wc + j][lane * 8];
#pragma unroll
        for (int i = 0; i < 4; ++i)
#pragma unroll
            for (int j = 0; j < 4; ++j)
                acc[i][j] = __builtin_amdgcn_mfma_f32_16x16x32_f16(a[i], b2[j], acc[i][j], 0, 0, 0);
    }

#pragma unroll
    for (int i = 0; i < 4; ++i)
#pragma unroll
        for (int r = 0; r < 4; ++r) {
            const int row = q0 + (wr + i) * 16 + lq * 4 + r;
#pragma unroll
            for (int j = 0; j < 4; ++j) {
                const int col = d0 + (wc + j) * 16 + lr;
                Ob[(size_t)row * Dd + col] = acc[i][j][r];
            }
        }
}

}  // namespace

extern "C" void kernel_launch(void* const* d_in, const int* in_sizes, int n_in,
                              void* d_out, int out_size, void* d_ws, size_t ws_size,
                              hipStream_t stream)
{
    const float* X  = (const float*)d_in[0];
    const float* Wq = (const float*)d_in[1];
    const float* Wk = (const float*)d_in[2];
    const float* Wv = (const float*)d_in[3];

    // layout (MB offsets):
    //  [0,16) Xhi | [16,32) Xlo | [32,40) Wq/Wk hi/lo | [40,42) WvTh
    //  [44,48) GT hi/lo | [48,80) T hi/lo  (P overlays after scores)
    //  [80,96) Vt | [96,112) Vrow -- S fp32 overlays [96,160)
    //  [160,..) stats
    char* ws = (char*)d_ws;
    const size_t MB = 1024 * 1024;
    _Float16* Xhi  = (_Float16*)ws;
    _Float16* Xlo  = (_Float16*)(ws + 16 * MB);
    _Float16* Wqh  = (_Float16*)(ws + 32 * MB);
    _Float16* Wql  = (_Float16*)(ws + 34 * MB);
    _Float16* Wkh  = (_Float16*)(ws + 36 * MB);
    _Float16* Wkl  = (_Float16*)(ws + 38 * MB);
    _Float16* WvTh = (_Float16*)(ws + 40 * MB);
    _Float16* GTh  = (_Float16*)(ws + 44 * MB);
    _Float16* GTl  = (_Float16*)(ws + 46 * MB);
    _Float16* Thi  = (_Float16*)(ws + 48 * MB);
    _Float16* Tlo  = (_Float16*)(ws + 64 * MB);
    _Float16* P    = Thi;                             // overlay after scores
    _Float16* Vt   = (_Float16*)(ws + 80 * MB);
    _Float16* Vrow = (_Float16*)(ws + 96 * MB);
    float*    S    = (float*)(ws + 96 * MB);          // overlays Vrow (dead)
    float*    Mb   = (float*)(ws + 160 * MB);
    float*    Lb   = Mb + (size_t)Bb * Tt;
    float*    Pm   = Lb + (size_t)Bb * Tt;
    float*    Pl   = Pm + (size_t)Bb * NCH * Tt;
    float*    Out  = (float*)d_out;

    convert_x_kernel<<<BT * Dd / 1024, 256, 0, stream>>>(X, Xhi, Xlo);
    convert_wqk_kernel<<<dim3(Dd * Dd / 1024, 2), 256, 0, stream>>>(Wq, Wk, Wqh, Wql, Wkh, Wkl);
    convert_wv_kernel<<<dim3(16, 16), 256, 0, stream>>>(Wv, WvTh);
    gt_kernel<<<dim3(16, 16), 256, 0, stream>>>(Wkh, Wkl, Wqh, Wql, GTh, GTl);
    tv_kernel<<<dim3(16, 64), 256, 0, stream>>>(Xhi, Xlo, GTh, GTl, WvTh, Thi, Tlo, Vrow);
    transpose_v_kernel<<<dim3(Dd / 64, Tt / 64, Bb), 256, 0, stream>>>(Vrow, Vt);
    scores_mfma_kernel<<<dim3(136, 1, Bb), 256, 0, stream>>>(Thi, Tlo, Xhi, Xlo, S);
    colstats_part_kernel<<<dim3(Tt / 256, NCH, Bb), 256, 0, stream>>>(S, Pm, Pl);
    colstats_merge_kernel<<<dim3(Tt / 256, Bb), 256, 0, stream>>>(Pm, Pl, Mb, Lb);
    pmat_kernel<<<(int)(((size_t)Bb * Tt * Tt / 8) / 256), 256, 0, stream>>>(S, Mb, Lb, P);
    context_mfma_kernel<<<dim3(Dd / 128, Tt / 128, Bb), 256, 0, stream>>>(P, Vt, Out);
}

// Round 8
// 456.610 us; speedup vs baseline: 4.3780x; 1.0999x over previous
//
#include <hip/hip_runtime.h>
#include <math.h>

typedef _Float16 half4 __attribute__((ext_vector_type(4)));
typedef _Float16 half8 __attribute__((ext_vector_type(8)));
typedef float f32x4 __attribute__((ext_vector_type(4)));

#define GLD16(gptr, lptr)                                                     \
    __builtin_amdgcn_global_load_lds(                                         \
        (const __attribute__((address_space(1))) unsigned int*)(gptr),        \
        (__attribute__((address_space(3))) unsigned int*)(lptr), 16, 0, 0)

namespace {

constexpr int Bb = 4;
constexpr int Tt = 2048;
constexpr int Dd = 1024;
constexpr int BT = Bb * Tt;   // 8192
constexpr int NCH = 16;       // stats chunks = 128-row tiles

__device__ inline _Float16 f2h(float f) { return (_Float16)f; }

// ---------------------------------------------------------------------------
// convert X: fp32 [BT][D] -> Xhi, Xlo fp16
// ---------------------------------------------------------------------------
__global__ __launch_bounds__(256) void convert_x_kernel(
    const float* __restrict__ X, _Float16* __restrict__ Xhi, _Float16* __restrict__ Xlo)
{
    const int idx = (blockIdx.x * 256 + threadIdx.x) * 4;
    const float4 v = *(const float4*)(X + idx);
    const float a[4] = {v.x, v.y, v.z, v.w};
    half4 h, l;
#pragma unroll
    for (int i = 0; i < 4; ++i) {
        h[i] = f2h(a[i]);
        l[i] = f2h(a[i] - (float)h[i]);
    }
    *(half4*)(Xhi + idx) = h;
    *(half4*)(Xlo + idx) = l;
}

// ---------------------------------------------------------------------------
// convert Wq,Wk (NO transpose): fp32 [r][a] -> hi/lo fp16 [r][a]
// ---------------------------------------------------------------------------
__global__ __launch_bounds__(256) void convert_wqk_kernel(
    const float* __restrict__ Wq, const float* __restrict__ Wk,
    _Float16* __restrict__ Wqh, _Float16* __restrict__ Wql,
    _Float16* __restrict__ Wkh, _Float16* __restrict__ Wkl)
{
    const int mat = blockIdx.y;
    const float* W = mat ? Wk : Wq;
    _Float16* Hh = mat ? Wkh : Wqh;
    _Float16* Ll = mat ? Wkl : Wql;
    const int idx = (blockIdx.x * 256 + threadIdx.x) * 4;
    const float4 v = *(const float4*)(W + idx);
    const float a[4] = {v.x, v.y, v.z, v.w};
    half4 h, l;
#pragma unroll
    for (int i = 0; i < 4; ++i) {
        h[i] = f2h(a[i]);
        l[i] = f2h(a[i] - (float)h[i]);
    }
    *(half4*)(Hh + idx) = h;
    *(half4*)(Ll + idx) = l;
}

// ---------------------------------------------------------------------------
// convert+transpose Wv: fp32 Wv[r][n] -> WvT[n][r] hi fp16
// ---------------------------------------------------------------------------
__global__ __launch_bounds__(256) void convert_wv_kernel(
    const float* __restrict__ Wv, _Float16* __restrict__ WvTh)
{
    __shared__ float tile[64][65];
    const int n0 = blockIdx.x * 64, k0 = blockIdx.y * 64;
    const int tx = threadIdx.x & 63, ty = threadIdx.x >> 6;
#pragma unroll
    for (int i = 0; i < 16; ++i)
        tile[ty + i * 4][tx] = Wv[(size_t)(k0 + ty + i * 4) * Dd + n0 + tx];
    __syncthreads();
#pragma unroll
    for (int i = 0; i < 16; ++i) {
        const float v = tile[tx][ty + i * 4];
        WvTh[(size_t)(n0 + ty + i * 4) * Dd + k0 + tx] = f2h(v);
    }
}

// ---------------------------------------------------------------------------
// GT[s][r] = sum_a Wk[s][a] * Wq[r][a]
// ---------------------------------------------------------------------------
__global__ __launch_bounds__(256) void gt_kernel(
    const _Float16* __restrict__ Wkh, const _Float16* __restrict__ Wkl,
    const _Float16* __restrict__ Wqh, const _Float16* __restrict__ Wql,
    _Float16* __restrict__ GTh, _Float16* __restrict__ GTl)
{
    __shared__ _Float16 Ahl[2][4][512];
    __shared__ _Float16 Bhl[2][4][512];

    const int n0 = blockIdx.x * 64;
    const int m0 = blockIdx.y * 64;
    const int tid = threadIdx.x;
    const int w = tid >> 6, lane = tid & 63;
    const int lr = lane & 15, lq = lane >> 4;
    const int wi = (w >> 1) * 2, wj = (w & 1) * 2;

    f32x4 acc[2][2];
#pragma unroll
    for (int i = 0; i < 2; ++i)
#pragma unroll
        for (int j = 0; j < 2; ++j)
#pragma unroll
            for (int c = 0; c < 4; ++c) acc[i][j][c] = 0.f;

    for (int kk = 0; kk < 1024; kk += 32) {
        __syncthreads();
        {
            const int s = w;
            const size_t ar = (size_t)(m0 + s * 16 + lr) * Dd + kk + lq * 8;
            const size_t br = (size_t)(n0 + s * 16 + lr) * Dd + kk + lq * 8;
            GLD16(Wkh + ar, &Ahl[0][s][0]);
            GLD16(Wkl + ar, &Ahl[1][s][0]);
            GLD16(Wqh + br, &Bhl[0][s][0]);
            GLD16(Wql + br, &Bhl[1][s][0]);
        }
        __syncthreads();
        half8 ah[2], al[2], bh[2], bl[2];
#pragma unroll
        for (int i = 0; i < 2; ++i) {
            ah[i] = *(const half8*)&Ahl[0][wi + i][lane * 8];
            al[i] = *(const half8*)&Ahl[1][wi + i][lane * 8];
        }
#pragma unroll
        for (int j = 0; j < 2; ++j) {
            bh[j] = *(const half8*)&Bhl[0][wj + j][lane * 8];
            bl[j] = *(const half8*)&Bhl[1][wj + j][lane * 8];
        }
#pragma unroll
        for (int i = 0; i < 2; ++i)
#pragma unroll
            for (int j = 0; j < 2; ++j) {
                acc[i][j] = __builtin_amdgcn_mfma_f32_16x16x32_f16(ah[i], bh[j], acc[i][j], 0, 0, 0);
                acc[i][j] = __builtin_amdgcn_mfma_f32_16x16x32_f16(ah[i], bl[j], acc[i][j], 0, 0, 0);
                acc[i][j] = __builtin_amdgcn_mfma_f32_16x16x32_f16(al[i], bh[j], acc[i][j], 0, 0, 0);
            }
    }

#pragma unroll
    for (int i = 0; i < 2; ++i)
#pragma unroll
        for (int r = 0; r < 4; ++r) {
            const int row = m0 + (wi + i) * 16 + lq * 4 + r;
#pragma unroll
            for (int j = 0; j < 2; ++j) {
                const int col = n0 + (wj + j) * 16 + lr;
                const float v = acc[i][j][r];
                const _Float16 h = f2h(v);
                GTh[(size_t)row * Dd + col] = h;
                GTl[(size_t)row * Dd + col] = f2h(v - (float)h);
            }
        }
}

// ---------------------------------------------------------------------------
// T = X*G (3 products, B-rows = GT), out T hi/lo.  128x128 tile template.
// ---------------------------------------------------------------------------
__global__ __launch_bounds__(256) void t_kernel(
    const _Float16* __restrict__ Xhi, const _Float16* __restrict__ Xlo,
    const _Float16* __restrict__ GTh, const _Float16* __restrict__ GTl,
    _Float16* __restrict__ Thi, _Float16* __restrict__ Tlo)
{
    __shared__ _Float16 Ahl[2][8][512];
    __shared__ _Float16 Bhl[2][8][512];

    const int n0 = blockIdx.x * 128;
    const int m0 = blockIdx.y * 128;
    const int tid = threadIdx.x;
    const int w = tid >> 6, lane = tid & 63;
    const int lr = lane & 15, lq = lane >> 4;
    const int wr = (w >> 1) * 4, wc = (w & 1) * 4;

    f32x4 acc[4][4];
#pragma unroll
    for (int i = 0; i < 4; ++i)
#pragma unroll
        for (int j = 0; j < 4; ++j)
#pragma unroll
            for (int c = 0; c < 4; ++c) acc[i][j][c] = 0.f;

    for (int kk = 0; kk < 1024; kk += 32) {
        __syncthreads();
#pragma unroll
        for (int s2 = 0; s2 < 2; ++s2) {
            const int s = w * 2 + s2;
            const size_t ar = (size_t)(m0 + s * 16 + lr) * Dd + kk + lq * 8;
            const size_t br = (size_t)(n0 + s * 16 + lr) * Dd + kk + lq * 8;
            GLD16(Xhi + ar, &Ahl[0][s][0]);
            GLD16(Xlo + ar, &Ahl[1][s][0]);
            GLD16(GTh + br, &Bhl[0][s][0]);
            GLD16(GTl + br, &Bhl[1][s][0]);
        }
        __syncthreads();
        half8 ah[4], al[4], bh[4], bl[4];
#pragma unroll
        for (int i = 0; i < 4; ++i) {
            ah[i] = *(const half8*)&Ahl[0][wr + i][lane * 8];
            al[i] = *(const half8*)&Ahl[1][wr + i][lane * 8];
        }
#pragma unroll
        for (int j = 0; j < 4; ++j) {
            bh[j] = *(const half8*)&Bhl[0][wc + j][lane * 8];
            bl[j] = *(const half8*)&Bhl[1][wc + j][lane * 8];
        }
#pragma unroll
        for (int i = 0; i < 4; ++i)
#pragma unroll
            for (int j = 0; j < 4; ++j) {
                acc[i][j] = __builtin_amdgcn_mfma_f32_16x16x32_f16(ah[i], bh[j], acc[i][j], 0, 0, 0);
                acc[i][j] = __builtin_amdgcn_mfma_f32_16x16x32_f16(ah[i], bl[j], acc[i][j], 0, 0, 0);
                acc[i][j] = __builtin_amdgcn_mfma_f32_16x16x32_f16(al[i], bh[j], acc[i][j], 0, 0, 0);
            }
    }
#pragma unroll
    for (int i = 0; i < 4; ++i)
#pragma unroll
        for (int r = 0; r < 4; ++r) {
            const int row = m0 + (wr + i) * 16 + lq * 4 + r;
#pragma unroll
            for (int j = 0; j < 4; ++j) {
                const int col = n0 + (wc + j) * 16 + lr;
                const float v = acc[i][j][r];
                const _Float16 h = f2h(v);
                Thi[(size_t)row * Dd + col] = h;
                Tlo[(size_t)row * Dd + col] = f2h(v - (float)h);
            }
        }
}

// ---------------------------------------------------------------------------
// V = X*Wv (single hi product), out fp16 row-major.
// ---------------------------------------------------------------------------
__global__ __launch_bounds__(256) void v_kernel(
    const _Float16* __restrict__ Xhi, const _Float16* __restrict__ WvTh,
    _Float16* __restrict__ Vrow)
{
    __shared__ _Float16 Al[8][512];
    __shared__ _Float16 Bl[8][512];

    const int n0 = blockIdx.x * 128;
    const int m0 = blockIdx.y * 128;
    const int tid = threadIdx.x;
    const int w = tid >> 6, lane = tid & 63;
    const int lr = lane & 15, lq = lane >> 4;
    const int wr = (w >> 1) * 4, wc = (w & 1) * 4;

    f32x4 acc[4][4];
#pragma unroll
    for (int i = 0; i < 4; ++i)
#pragma unroll
        for (int j = 0; j < 4; ++j)
#pragma unroll
            for (int c = 0; c < 4; ++c) acc[i][j][c] = 0.f;

    for (int kk = 0; kk < 1024; kk += 32) {
        __syncthreads();
#pragma unroll
        for (int s2 = 0; s2 < 2; ++s2) {
            const int s = w * 2 + s2;
            GLD16(Xhi + (size_t)(m0 + s * 16 + lr) * Dd + kk + lq * 8, &Al[s][0]);
            GLD16(WvTh + (size_t)(n0 + s * 16 + lr) * Dd + kk + lq * 8, &Bl[s][0]);
        }
        __syncthreads();
        half8 a[4], b2[4];
#pragma unroll
        for (int i = 0; i < 4; ++i) a[i] = *(const half8*)&Al[wr + i][lane * 8];
#pragma unroll
        for (int j = 0; j < 4; ++j) b2[j] = *(const half8*)&Bl[wc + j][lane * 8];
#pragma unroll
        for (int i = 0; i < 4; ++i)
#pragma unroll
            for (int j = 0; j < 4; ++j)
                acc[i][j] = __builtin_amdgcn_mfma_f32_16x16x32_f16(a[i], b2[j], acc[i][j], 0, 0, 0);
    }
#pragma unroll
    for (int i = 0; i < 4; ++i)
#pragma unroll
        for (int r = 0; r < 4; ++r) {
            const int row = m0 + (wr + i) * 16 + lq * 4 + r;
#pragma unroll
            for (int j = 0; j < 4; ++j)
                Vrow[(size_t)row * Dd + n0 + (wc + j) * 16 + lr] = f2h(acc[i][j][r]);
        }
}

// ---------------------------------------------------------------------------
// transpose V + fold invl: Vt[b][d][t] = Vrow[b][t][d] * invl[b][t]
// (runs AFTER colstats_merge)
// ---------------------------------------------------------------------------
__global__ __launch_bounds__(256) void transpose_v_kernel(
    const _Float16* __restrict__ Vrow, const float* __restrict__ Lb,
    _Float16* __restrict__ Vt)
{
    __shared__ _Float16 tile[64][78];
    const int d0 = blockIdx.x * 64, t0 = blockIdx.y * 64, b = blockIdx.z;
    const int tx = threadIdx.x & 63, ty = threadIdx.x >> 6;
#pragma unroll
    for (int i = 0; i < 16; ++i)
        tile[ty + i * 4][tx] = Vrow[((size_t)b * Tt + t0 + ty + i * 4) * Dd + d0 + tx];
    __syncthreads();
    const float sc = Lb[(size_t)b * Tt + t0 + tx];
#pragma unroll
    for (int i = 0; i < 16; ++i) {
        const float v = (float)tile[tx][ty + i * 4] * sc;
        Vt[(size_t)b * Dd * Tt + (size_t)(d0 + ty + i * 4) * Tt + t0 + tx] = f2h(v);
    }
}

// ---------------------------------------------------------------------------
// scores + FUSED column stats.  Lower-triangle tiles; per tile writes
// S (fp32) and per-column partial (max, sumexp) at chunk index byi.
// ---------------------------------------------------------------------------
__global__ __launch_bounds__(256) void scores_mfma_kernel(
    const _Float16* __restrict__ Thi, const _Float16* __restrict__ Tlo,
    const _Float16* __restrict__ Xhi, const _Float16* __restrict__ Xlo,
    float* __restrict__ S, float* __restrict__ Pm, float* __restrict__ Pl)
{
    const int t = blockIdx.x;
    int byi = (int)((sqrtf(8.f * t + 1.f) - 1.f) * 0.5f);
    if ((byi + 1) * (byi + 2) / 2 <= t) ++byi;
    if (byi * (byi + 1) / 2 > t) --byi;
    const int bxi = t - byi * (byi + 1) / 2;
    const int b = blockIdx.z;
    const int j0 = bxi * 128, q0 = byi * 128;
    float* Sb = S + (size_t)b * Tt * Tt;

    __shared__ _Float16 Ahl[2][8][512];
    __shared__ _Float16 Bhl[2][8][512];
    const _Float16* Th = Thi + (size_t)b * Tt * Dd;
    const _Float16* Tl = Tlo + (size_t)b * Tt * Dd;
    const _Float16* Xh = Xhi + (size_t)b * Tt * Dd;
    const _Float16* Xl = Xlo + (size_t)b * Tt * Dd;

    const int tid = threadIdx.x;
    const int w = tid >> 6, lane = tid & 63;
    const int lr = lane & 15, lq = lane >> 4;
    const int wr = (w >> 1) * 4, wc = (w & 1) * 4;

    f32x4 acc[4][4];
#pragma unroll
    for (int i = 0; i < 4; ++i)
#pragma unroll
        for (int j = 0; j < 4; ++j)
#pragma unroll
            for (int c = 0; c < 4; ++c) acc[i][j][c] = 0.f;

    for (int kk = 0; kk < 1024; kk += 32) {
        __syncthreads();
#pragma unroll
        for (int s2 = 0; s2 < 2; ++s2) {
            const int s = w * 2 + s2;
            const size_t ar = (size_t)(q0 + s * 16 + lr) * Dd + kk + lq * 8;
            const size_t br = (size_t)(j0 + s * 16 + lr) * Dd + kk + lq * 8;
            GLD16(Th + ar, &Ahl[0][s][0]);
            GLD16(Tl + ar, &Ahl[1][s][0]);
            GLD16(Xh + br, &Bhl[0][s][0]);
            GLD16(Xl + br, &Bhl[1][s][0]);
        }
        __syncthreads();
        half8 ah[4], al[4], bh[4], bl[4];
#pragma unroll
        for (int i = 0; i < 4; ++i) {
            ah[i] = *(const half8*)&Ahl[0][wr + i][lane * 8];
            al[i] = *(const half8*)&Ahl[1][wr + i][lane * 8];
        }
#pragma unroll
        for (int j = 0; j < 4; ++j) {
            bh[j] = *(const half8*)&Bhl[0][wc + j][lane * 8];
            bl[j] = *(const half8*)&Bhl[1][wc + j][lane * 8];
        }
#pragma unroll
        for (int i = 0; i < 4; ++i)
#pragma unroll
            for (int j = 0; j < 4; ++j) {
                acc[i][j] = __builtin_amdgcn_mfma_f32_16x16x32_f16(ah[i], bh[j], acc[i][j], 0, 0, 0);
                acc[i][j] = __builtin_amdgcn_mfma_f32_16x16x32_f16(ah[i], bl[j], acc[i][j], 0, 0, 0);
                acc[i][j] = __builtin_amdgcn_mfma_f32_16x16x32_f16(al[i], bh[j], acc[i][j], 0, 0, 0);
            }
    }

    // masked values + S store
    float sv[4][4][4];
#pragma unroll
    for (int i = 0; i < 4; ++i)
#pragma unroll
        for (int r = 0; r < 4; ++r) {
            const int q = q0 + (wr + i) * 16 + lq * 4 + r;
#pragma unroll
            for (int j = 0; j < 4; ++j) {
                const int jg = j0 + (wc + j) * 16 + lr;
                const float v = (jg <= q) ? floorf(acc[i][j][r] * 0.03125f) : -INFINITY;
                sv[i][j][r] = v;
                Sb[(size_t)q * Tt + jg] = v;
            }
        }

    // fused per-column stats (reuse staging LDS: 16x128 partials + 128 colmax)
    float* red  = (float*)&Ahl[0][0][0];   // [16][128]
    float* colm = red + 2048;              // [128]
    __syncthreads();
    for (int e = tid; e < 2048; e += 256) red[e] = -INFINITY;
    __syncthreads();
    const int rowidx = (w * 4 + lq) * 128;
#pragma unroll
    for (int j = 0; j < 4; ++j) {
        const int c = (wc + j) * 16 + lr;
        float lm = -INFINITY;
#pragma unroll
        for (int i = 0; i < 4; ++i)
#pragma unroll
            for (int r = 0; r < 4; ++r) lm = fmaxf(lm, sv[i][j][r]);
        red[rowidx + c] = lm;
    }
    __syncthreads();
    if (tid < 128) {
        float m = -INFINITY;
#pragma unroll
        for (int e = 0; e < 16; ++e) m = fmaxf(m, red[e * 128 + tid]);
        colm[tid] = m;
    }
    __syncthreads();
    float ls[4];
#pragma unroll
    for (int j = 0; j < 4; ++j) {
        const int c = (wc + j) * 16 + lr;
        const float m = colm[c];
        float s = 0.f;
#pragma unroll
        for (int i = 0; i < 4; ++i)
#pragma unroll
            for (int r = 0; r < 4; ++r)
                if (sv[i][j][r] != -INFINITY) s += __expf(sv[i][j][r] - m);
        ls[j] = s;
    }
    __syncthreads();
    for (int e = tid; e < 2048; e += 256) red[e] = 0.f;
    __syncthreads();
#pragma unroll
    for (int j = 0; j < 4; ++j) red[rowidx + (wc + j) * 16 + lr] = ls[j];
    __syncthreads();
    if (tid < 128) {
        float l = 0.f;
#pragma unroll
        for (int e = 0; e < 16; ++e) l += red[e * 128 + tid];
        const size_t o = ((size_t)b * NCH + byi) * Tt + j0 + tid;
        Pm[o] = colm[tid];
        Pl[o] = l;
    }
}

// ---------------------------------------------------------------------------
// merge NCH=16 partials per column -> m, 1/l  (index-predicated: c >= j>>7)
// ---------------------------------------------------------------------------
__global__ __launch_bounds__(256) void colstats_merge_kernel(
    const float* __restrict__ Pm, const float* __restrict__ Pl,
    float* __restrict__ Mb, float* __restrict__ Lb)
{
    const int j = blockIdx.x * 256 + threadIdx.x;
    const int b = blockIdx.y;
    const int jt = j >> 7;
    float m = -INFINITY, l = 0.f;
    for (int c = jt; c < NCH; ++c) {
        const size_t pidx = ((size_t)b * NCH + c) * Tt + j;
        const float mi = Pm[pidx];
        if (mi == -INFINITY) continue;
        const float li = Pl[pidx];
        if (mi > m) { l = l * __expf(m - mi) + li; m = mi; }
        else        { l += li * __expf(mi - m); }
    }
    Mb[(size_t)b * Tt + j] = m;
    Lb[(size_t)b * Tt + j] = (l > 0.f) ? 1.f / l : 0.f;
}

// ---------------------------------------------------------------------------
// P = exp(S - m[k]) fp16 over LOWER tiles only (diagonal: 0 above diag).
// ---------------------------------------------------------------------------
__global__ __launch_bounds__(256) void pmat_kernel(
    const float* __restrict__ S, const float* __restrict__ Mb,
    _Float16* __restrict__ P)
{
    const int t = blockIdx.x;
    int byi = (int)((sqrtf(8.f * t + 1.f) - 1.f) * 0.5f);
    if ((byi + 1) * (byi + 2) / 2 <= t) ++byi;
    if (byi * (byi + 1) / 2 > t) --byi;
    const int bxi = t - byi * (byi + 1) / 2;
    const int b = blockIdx.z;
    const int j0 = bxi * 128, q0 = byi * 128;

    const int tr = threadIdx.x >> 4;            // 0..15
    const int tc = (threadIdx.x & 15) * 8;      // col offset in tile
    const float* mp = Mb + (size_t)b * Tt + j0 + tc;
    float mv[8];
#pragma unroll
    for (int e = 0; e < 8; ++e) mv[e] = mp[e];

#pragma unroll
    for (int it = 0; it < 8; ++it) {
        const int row = q0 + it * 16 + tr;
        const float* Sp = S + (size_t)b * Tt * Tt + (size_t)row * Tt + j0 + tc;
        const float4 s0 = *(const float4*)Sp;
        const float4 s1 = *(const float4*)(Sp + 4);
        const float sa[8] = {s0.x, s0.y, s0.z, s0.w, s1.x, s1.y, s1.z, s1.w};
        half8 out;
#pragma unroll
        for (int e = 0; e < 8; ++e) {
            const int jg = j0 + tc + e;
            out[e] = (jg <= row) ? f2h(__expf(sa[e] - mv[e])) : (_Float16)0.f;
        }
        *(half8*)(P + (size_t)b * Tt * Tt + (size_t)row * Tt + j0 + tc) = out;
    }
}

// ---------------------------------------------------------------------------
// context = P @ Vscaled.  Single-product fp16 MFMA, causal k-truncation.
// ---------------------------------------------------------------------------
__global__ __launch_bounds__(256) void context_mfma_kernel(
    const _Float16* __restrict__ P, const _Float16* __restrict__ Vt,
    float* __restrict__ Out)
{
    __shared__ _Float16 Al[8][512];
    __shared__ _Float16 Bl[8][512];

    const int bx = blockIdx.x;
    const int by = (int)gridDim.y - 1 - blockIdx.y;  // heavy q-blocks first
    const int b  = blockIdx.z;
    const int d0 = bx * 128;
    const int q0 = by * 128;
    const _Float16* Pb = P + (size_t)b * Tt * Tt;
    const _Float16* Vb = Vt + (size_t)b * Dd * Tt;
    float* Ob = Out + (size_t)b * Tt * Dd;

    const int tid = threadIdx.x;
    const int w = tid >> 6, lane = tid & 63;
    const int lr = lane & 15, lq = lane >> 4;
    const int wr = (w >> 1) * 4, wc = (w & 1) * 4;

    f32x4 acc[4][4];
#pragma unroll
    for (int i = 0; i < 4; ++i)
#pragma unroll
        for (int j = 0; j < 4; ++j)
#pragma unroll
            for (int c = 0; c < 4; ++c) acc[i][j][c] = 0.f;

    const int kmax = q0 + 128;
    for (int k0 = 0; k0 < kmax; k0 += 32) {
        __syncthreads();
#pragma unroll
        for (int s2 = 0; s2 < 2; ++s2) {
            const int s = w * 2 + s2;
            GLD16(Pb + (size_t)(q0 + s * 16 + lr) * Tt + k0 + lq * 8, &Al[s][0]);
            GLD16(Vb + (size_t)(d0 + s * 16 + lr) * Tt + k0 + lq * 8, &Bl[s][0]);
        }
        __syncthreads();
        half8 a[4], b2[4];
#pragma unroll
        for (int i = 0; i < 4; ++i) a[i] = *(const half8*)&Al[wr + i][lane * 8];
#pragma unroll
        for (int j = 0; j < 4; ++j) b2[j] = *(const half8*)&Bl[wc + j][lane * 8];
#pragma unroll
        for (int i = 0; i < 4; ++i)
#pragma unroll
            for (int j = 0; j < 4; ++j)
                acc[i][j] = __builtin_amdgcn_mfma_f32_16x16x32_f16(a[i], b2[j], acc[i][j], 0, 0, 0);
    }

#pragma unroll
    for (int i = 0; i < 4; ++i)
#pragma unroll
        for (int r = 0; r < 4; ++r) {
            const int row = q0 + (wr + i) * 16 + lq * 4 + r;
#pragma unroll
            for (int j = 0; j < 4; ++j)
                Ob[(size_t)row * Dd + d0 + (wc + j) * 16 + lr] = acc[i][j][r];
        }
}

}  // namespace

extern "C" void kernel_launch(void* const* d_in, const int* in_sizes, int n_in,
                              void* d_out, int out_size, void* d_ws, size_t ws_size,
                              hipStream_t stream)
{
    const float* X  = (const float*)d_in[0];
    const float* Wq = (const float*)d_in[1];
    const float* Wk = (const float*)d_in[2];
    const float* Wv = (const float*)d_in[3];

    char* ws = (char*)d_ws;
    const size_t MB = 1024 * 1024;
    _Float16* Xhi  = (_Float16*)ws;
    _Float16* Xlo  = (_Float16*)(ws + 16 * MB);
    _Float16* Wqh  = (_Float16*)(ws + 32 * MB);
    _Float16* Wql  = (_Float16*)(ws + 34 * MB);
    _Float16* Wkh  = (_Float16*)(ws + 36 * MB);
    _Float16* Wkl  = (_Float16*)(ws + 38 * MB);
    _Float16* WvTh = (_Float16*)(ws + 40 * MB);
    _Float16* GTh  = (_Float16*)(ws + 44 * MB);
    _Float16* GTl  = (_Float16*)(ws + 46 * MB);
    _Float16* Thi  = (_Float16*)(ws + 48 * MB);
    _Float16* Tlo  = (_Float16*)(ws + 64 * MB);
    _Float16* P    = Thi;                             // overlay after scores (32 MB)
    _Float16* Vt   = (_Float16*)(ws + 80 * MB);
    _Float16* Vrow = (_Float16*)(ws + 96 * MB);
    float*    S    = (float*)(ws + 112 * MB);         // 64 MB
    float*    Mb   = (float*)(ws + 176 * MB);
    float*    Lb   = Mb + (size_t)Bb * Tt;
    float*    Pm   = Lb + (size_t)Bb * Tt;
    float*    Pl   = Pm + (size_t)Bb * NCH * Tt;
    float*    Out  = (float*)d_out;

    convert_x_kernel<<<BT * Dd / 1024, 256, 0, stream>>>(X, Xhi, Xlo);
    convert_wqk_kernel<<<dim3(Dd * Dd / 1024, 2), 256, 0, stream>>>(Wq, Wk, Wqh, Wql, Wkh, Wkl);
    convert_wv_kernel<<<dim3(16, 16), 256, 0, stream>>>(Wv, WvTh);
    gt_kernel<<<dim3(16, 16), 256, 0, stream>>>(Wkh, Wkl, Wqh, Wql, GTh, GTl);
    t_kernel<<<dim3(8, 64), 256, 0, stream>>>(Xhi, Xlo, GTh, GTl, Thi, Tlo);
    v_kernel<<<dim3(8, 64), 256, 0, stream>>>(Xhi, WvTh, Vrow);
    scores_mfma_kernel<<<dim3(136, 1, Bb), 256, 0, stream>>>(Thi, Tlo, Xhi, Xlo, S, Pm, Pl);
    colstats_merge_kernel<<<dim3(Tt / 256, Bb), 256, 0, stream>>>(Pm, Pl, Mb, Lb);
    transpose_v_kernel<<<dim3(Dd / 64, Tt / 64, Bb), 256, 0, stream>>>(Vrow, Lb, Vt);
    pmat_kernel<<<dim3(136, 1, Bb), 256, 0, stream>>>(S, Mb, P);
    context_mfma_kernel<<<dim3(Dd / 128, Tt / 128, Bb), 256, 0, stream>>>(P, Vt, Out);
}